// Round 8
// baseline (350.237 us; speedup 1.0000x reference)
//
#include <hip/hip_runtime.h>
#include <math.h>

// ---------------- problem constants ----------------
constexpr int B_    = 2;
constexpr int L_    = 2048;
constexpr int NROW  = B_ * L_;     // 4096 rows per branch
constexpr int MROW  = 2 * NROW;    // 8192 merged rows (branch-major)
constexpr int HALF_ = 256;
constexpr int DS_   = 128;

constexpr float LOG2E = 1.4426950408889634f;

// ---------------- ws layout ----------------
// fp32 region (float element offsets)
constexpr size_t OFF_MINP = 0;                                    // 32 (minA partials)
constexpr size_t OFF_BCMX = 32;                                   // 4 (uint atomics: brB,brC x2)
constexpr size_t OFF_XZ   = 64;                                   // 8192x512 (transient)
constexpr size_t OFF_HIN  = OFF_XZ;                               // alias: 1024x128 h(t=1024) (XZ front half dead after conv)
constexpr size_t OFF_YT   = OFF_XZ + (size_t)MROW * 256;          // alias: 2x256x4096 (after conv)
constexpr size_t OFF_XDBL = OFF_XZ + (size_t)MROW * 512;          // 8192x288
constexpr size_t OFF_XS   = OFF_XDBL + (size_t)MROW * 288;        // 8192x256
constexpr size_t OFF_BS   = OFF_XS  + (size_t)MROW * 256;         // 2 x 4096x128
constexpr size_t OFF_CS   = OFF_BS  + (size_t)2 * NROW * 128;     // 2 x 4096x128
constexpr size_t OFF_DTT  = OFF_CS  + (size_t)2 * NROW * 128;     // 2 x 256x4096
constexpr size_t OFF_DUT  = OFF_DTT + (size_t)2 * 256 * 4096;
constexpr size_t OFF_UDT  = OFF_DUT + (size_t)2 * 256 * 4096;
constexpr size_t FLOAT_END = OFF_UDT + (size_t)2 * 256 * 4096;

// bf16 region (ushort element offsets, based at ws + FLOAT_END floats)
constexpr size_t HOFF_XINH = 0;                                   // 8192x512
constexpr size_t HOFF_XINL = HOFF_XINH + (size_t)MROW * 512;
constexpr size_t HOFF_YZH  = HOFF_XINH;                           // alias (xin dead after in_proj)
constexpr size_t HOFF_YZL  = HOFF_XINL;
constexpr size_t HOFF_XSH  = HOFF_XINL + (size_t)MROW * 512;      // 8192x256
constexpr size_t HOFF_XSL  = HOFF_XSH  + (size_t)MROW * 256;
constexpr size_t HOFF_INWH = HOFF_XSL  + (size_t)MROW * 256;      // 2 x 512x512
constexpr size_t HOFF_INWL = HOFF_INWH + 524288;
constexpr size_t HOFF_XWH  = HOFF_INWL + 524288;                  // 2 x 288x256
constexpr size_t HOFF_XWL  = HOFF_XWH  + 147456;
constexpr size_t HOFF_OUTWH= HOFF_XWL  + 147456;                  // 2 x 512x512
constexpr size_t HOFF_OUTWL= HOFF_OUTWH+ 524288;

constexpr size_t WST_IN = 262144;   // per-branch in/out weight elems
constexpr size_t WST_X  = 73728;    // per-branch x_proj weight elems

// pre_all block ranges
constexpr int PRE_MINA = 32;
constexpr int PRE_WSPL = (1196032 + 255) / 256;   // 4672
constexpr int PRE_TIN  = 64 * 16 * 4;             // 4096
constexpr int PRE_BLOCKS = PRE_MINA + PRE_WSPL + PRE_TIN;

// ---------------- types / helpers ----------------
typedef __bf16 bf16x8 __attribute__((ext_vector_type(8)));
typedef float  f32x4  __attribute__((ext_vector_type(4)));

__device__ __forceinline__ unsigned short bf16rn(float x) {
    unsigned u = __float_as_uint(x);
    unsigned r = (u + 0x7FFFu + ((u >> 16) & 1u)) >> 16;
    return (unsigned short)r;
}
__device__ __forceinline__ void split2(float x, unsigned short& h, unsigned short& l) {
    h = bf16rn(x);
    float hf = __uint_as_float(((unsigned)h) << 16);
    l = bf16rn(x - hf);
}

__device__ __forceinline__ float shrinkf(float v, float thr) {
    float a = fabsf(v) - thr;
    a = fmaxf(a, 0.0f);
    float r = copysignf(a, v);
    return (v == 0.0f) ? 0.0f : r;
}
__device__ __forceinline__ float siluf(float v) { return v / (1.0f + __expf(-v)); }
__device__ __forceinline__ float softplusf(float v) {
    return fmaxf(v, 0.0f) + log1pf(__expf(-fabsf(v)));
}
__device__ __forceinline__ float rlanef(float v, int l) {
    return __int_as_float(__builtin_amdgcn_readlane(__float_as_int(v), l));
}
// monotone float<->uint key for atomicMax on signed floats
__device__ __forceinline__ unsigned fkey(float f) {
    unsigned u = __float_as_uint(f);
    return (u >> 31) ? ~u : (u | 0x80000000u);
}
__device__ __forceinline__ float funkey(unsigned k) {
    unsigned u = (k >> 31) ? (k & 0x7FFFFFFFu) : ~k;
    return __uint_as_float(u);
}

// ---------------- pre_all: minA + weight splits + input transpose, one dispatch ----------------
__global__ __launch_bounds__(256) void pre_all(const float* __restrict__ A_log,
                                               const float* __restrict__ inp,
                                               const float* __restrict__ in_w0,
                                               const float* __restrict__ in_w1,
                                               const float* __restrict__ outw0,
                                               const float* __restrict__ outw1,
                                               const float* __restrict__ xw0,
                                               const float* __restrict__ xw1,
                                               float* __restrict__ ws,
                                               unsigned* __restrict__ bcmax,
                                               unsigned short* __restrict__ hb) {
    int bid = blockIdx.x;
    int tid = threadIdx.x;
    if (bid < PRE_MINA) {
        // ---- minA role ----
        __shared__ float sbuf[8];
        int i = bid * 1024 + tid * 4;
        float4 v = *(const float4*)(A_log + i);
        float mv = fminf(fminf(v.x, v.y), fminf(v.z, v.w));
        #pragma unroll
        for (int off = 32; off > 0; off >>= 1) mv = fminf(mv, __shfl_xor(mv, off));
        if ((tid & 63) == 0) sbuf[tid >> 6] = mv;
        __syncthreads();
        if (tid == 0) {
            float r = fminf(fminf(sbuf[0], sbuf[1]), fminf(sbuf[2], sbuf[3]));
            ws[OFF_MINP + bid] = r;
        }
        if (bid == 0 && tid < 4) bcmax[tid] = 0u;
    } else if (bid < PRE_MINA + PRE_WSPL) {
        // ---- wsplit role ----
        int i = (bid - PRE_MINA) * 256 + tid;
        if (i >= 1196032) return;
        const float* src;
        size_t hbase, lbase;
        int off;
        if (i < 1048576) {
            int t = i >> 18;
            off = i & 262143;
            src = (t == 0) ? in_w0 : (t == 1) ? in_w1 : (t == 2) ? outw0 : outw1;
            if (t < 2) { hbase = HOFF_INWH + (size_t)t * WST_IN;  lbase = HOFF_INWL + (size_t)t * WST_IN; }
            else       { hbase = HOFF_OUTWH + (size_t)(t - 2) * WST_IN; lbase = HOFF_OUTWL + (size_t)(t - 2) * WST_IN; }
        } else {
            int j = i - 1048576;
            int t = (j < (int)WST_X) ? 0 : 1;
            off = j - t * (int)WST_X;
            src = t ? xw1 : xw0;
            hbase = HOFF_XWH + (size_t)t * WST_X;
            lbase = HOFF_XWL + (size_t)t * WST_X;
        }
        unsigned short h, l;
        split2(src[off], h, l);
        hb[hbase + off] = h;
        hb[lbase + off] = l;
    } else {
        // ---- transpose_in role ----
        __shared__ float tile[32][33];
        int idx = bid - PRE_MINA - PRE_WSPL;    // 0..4095
        int bx = idx & 63;          // t block (64)
        int by = (idx >> 6) & 15;   // ch block (16)
        int z  = idx >> 10;         // 0..3
        int br = z >> 1;
        int b  = z & 1;
        int t0 = bx * 32;
        int m0 = by * 32;
        int tx = tid & 31;
        int ty = tid >> 5;
        #pragma unroll
        for (int k = 0; k < 4; k++) {
            tile[ty + 8 * k][tx] =
                inp[((size_t)b * 1024 + br * 512 + m0 + ty + 8 * k) * L_ + t0 + tx];
        }
        __syncthreads();
        #pragma unroll
        for (int k = 0; k < 4; k++) {
            size_t dst = ((size_t)br * NROW + (size_t)b * L_ + t0 + ty + 8 * k) * 512 + m0 + tx;
            unsigned short h, l;
            split2(tile[tx][ty + 8 * k], h, l);
            hb[HOFF_XINH + dst] = h;
            hb[HOFF_XINL + dst] = l;
        }
    }
}

// ---------------- MFMA GEMM (bf16x3) with register prefetch ----------------
// 128x64 tile, BK=32, 256 thr. Next K-chunk preloaded into registers right after
// the second barrier -> global latency overlaps the 24-MFMA compute phase.
template <int NGUARD, int DOMAX>
__global__ __launch_bounds__(256) void gemm_mfma(const unsigned short* __restrict__ Ah,
                                                 const unsigned short* __restrict__ Al, int lda,
                                                 const unsigned short* __restrict__ WhB,
                                                 const unsigned short* __restrict__ WlB,
                                                 size_t wstride,
                                                 float* __restrict__ C, int ldc,
                                                 int N, int K,
                                                 unsigned* __restrict__ bcmax) {
    __shared__ __align__(16) unsigned short sAh[128 * 40];
    __shared__ __align__(16) unsigned short sAl[128 * 40];
    __shared__ __align__(16) unsigned short sBh[64 * 40];
    __shared__ __align__(16) unsigned short sBl[64 * 40];
    int tid  = threadIdx.x;
    int wid  = tid >> 6;
    int lane = tid & 63;
    int fr   = lane & 15;
    int kg   = lane >> 4;
    int mblk = blockIdx.y * 128;
    int nblk = blockIdx.x * 64;
    int br   = (mblk >= NROW) ? 1 : 0;
    const unsigned short* Wh = WhB + (size_t)br * wstride;
    const unsigned short* Wl = WlB + (size_t)br * wstride;
    int srow = tid >> 2;            // 0..63
    int skp  = (tid & 3) * 8;       // k-chunk of 8
    bool brow_ok = (!NGUARD) || ((nblk + srow) < N);

    const unsigned short* pA0 = Ah + (size_t)(mblk + srow) * lda + skp;
    const unsigned short* pA1 = Ah + (size_t)(mblk + 64 + srow) * lda + skp;
    const unsigned short* pL0 = Al + (size_t)(mblk + srow) * lda + skp;
    const unsigned short* pL1 = Al + (size_t)(mblk + 64 + srow) * lda + skp;
    const unsigned short* pBh = Wh + (size_t)(nblk + srow) * K + skp;
    const unsigned short* pBl = Wl + (size_t)(nblk + srow) * K + skp;

    f32x4 acc[2][4] = {};

    uint4 rah0 = *(const uint4*)(pA0);
    uint4 rah1 = *(const uint4*)(pA1);
    uint4 ral0 = *(const uint4*)(pL0);
    uint4 ral1 = *(const uint4*)(pL1);
    uint4 rbh = {0, 0, 0, 0}, rbl = {0, 0, 0, 0};
    if (brow_ok) {
        rbh = *(const uint4*)(pBh);
        rbl = *(const uint4*)(pBl);
    }

    for (int k0 = 0; k0 < K; k0 += 32) {
        __syncthreads();   // WAR vs previous iter's ds_reads
        *(uint4*)(sAh + srow * 40 + skp) = rah0;
        *(uint4*)(sAh + (64 + srow) * 40 + skp) = rah1;
        *(uint4*)(sAl + srow * 40 + skp) = ral0;
        *(uint4*)(sAl + (64 + srow) * 40 + skp) = ral1;
        *(uint4*)(sBh + srow * 40 + skp) = rbh;
        *(uint4*)(sBl + srow * 40 + skp) = rbl;
        __syncthreads();

        int kn = k0 + 32;
        if (kn < K) {      // prefetch next chunk; latency hides under MFMAs below
            rah0 = *(const uint4*)(pA0 + kn);
            rah1 = *(const uint4*)(pA1 + kn);
            ral0 = *(const uint4*)(pL0 + kn);
            ral1 = *(const uint4*)(pL1 + kn);
            if (brow_ok) {
                rbh = *(const uint4*)(pBh + kn);
                rbl = *(const uint4*)(pBl + kn);
            }
        }

        bf16x8 ah0 = *(const bf16x8*)(sAh + (wid * 32 + fr) * 40 + kg * 8);
        bf16x8 ah1 = *(const bf16x8*)(sAh + (wid * 32 + 16 + fr) * 40 + kg * 8);
        bf16x8 al0 = *(const bf16x8*)(sAl + (wid * 32 + fr) * 40 + kg * 8);
        bf16x8 al1 = *(const bf16x8*)(sAl + (wid * 32 + 16 + fr) * 40 + kg * 8);
        #pragma unroll
        for (int nt = 0; nt < 4; nt++) {
            bf16x8 bh = *(const bf16x8*)(sBh + (nt * 16 + fr) * 40 + kg * 8);
            bf16x8 bl = *(const bf16x8*)(sBl + (nt * 16 + fr) * 40 + kg * 8);
            acc[0][nt] = __builtin_amdgcn_mfma_f32_16x16x32_bf16(ah0, bh, acc[0][nt], 0, 0, 0);
            acc[0][nt] = __builtin_amdgcn_mfma_f32_16x16x32_bf16(ah0, bl, acc[0][nt], 0, 0, 0);
            acc[0][nt] = __builtin_amdgcn_mfma_f32_16x16x32_bf16(al0, bh, acc[0][nt], 0, 0, 0);
            acc[1][nt] = __builtin_amdgcn_mfma_f32_16x16x32_bf16(ah1, bh, acc[1][nt], 0, 0, 0);
            acc[1][nt] = __builtin_amdgcn_mfma_f32_16x16x32_bf16(ah1, bl, acc[1][nt], 0, 0, 0);
            acc[1][nt] = __builtin_amdgcn_mfma_f32_16x16x32_bf16(al1, bh, acc[1][nt], 0, 0, 0);
        }
    }
    // C/D layout: col = lane&15, row = (lane>>4)*4 + reg
    #pragma unroll
    for (int mt = 0; mt < 2; mt++) {
        #pragma unroll
        for (int nt = 0; nt < 4; nt++) {
            int col = nblk + nt * 16 + fr;
            if (NGUARD && col >= N) continue;
            #pragma unroll
            for (int r = 0; r < 4; r++) {
                int row = mblk + wid * 32 + mt * 16 + kg * 4 + r;
                C[(size_t)row * ldc + col] = acc[mt][nt][r];
            }
        }
    }
    if (DOMAX) {
        float mb = -INFINITY, mc = -INFINITY;
        #pragma unroll
        for (int nt = 0; nt < 4; nt++) {
            int c16 = nblk + nt * 16;
            if (c16 >= 32 && c16 < 160) {
                #pragma unroll
                for (int mt = 0; mt < 2; mt++)
                    #pragma unroll
                    for (int r = 0; r < 4; r++) mb = fmaxf(mb, acc[mt][nt][r]);
            } else if (c16 >= 160 && c16 < 288) {
                #pragma unroll
                for (int mt = 0; mt < 2; mt++)
                    #pragma unroll
                    for (int r = 0; r < 4; r++) mc = fmaxf(mc, acc[mt][nt][r]);
            }
        }
        #pragma unroll
        for (int off = 32; off > 0; off >>= 1) {
            mb = fmaxf(mb, __shfl_xor(mb, off));
            mc = fmaxf(mc, __shfl_xor(mc, off));
        }
        if (lane == 0) {
            if (mb > -INFINITY) atomicMax(bcmax + 2 * br,     fkey(mb));
            if (mc > -INFINITY) atomicMax(bcmax + 2 * br + 1, fkey(mc));
        }
    }
}

// ---------------- depthwise conv (k=4) + SiLU, vectorized 4 channels/thread ----------------
__global__ __launch_bounds__(256) void conv_silu_kernel(const float* __restrict__ xz,
                                                        float* __restrict__ xs,
                                                        unsigned short* __restrict__ xsh,
                                                        unsigned short* __restrict__ xsl,
                                                        unsigned short* __restrict__ yzh,
                                                        unsigned short* __restrict__ yzl,
                                                        const float* __restrict__ wx0,
                                                        const float* __restrict__ wx1,
                                                        const float* __restrict__ wz0,
                                                        const float* __restrict__ wz1) {
    int gid = blockIdx.x * 256 + threadIdx.x;   // over MROW*64
    int c4  = (gid & 63) << 2;                  // channel quad
    int row = gid >> 6;                         // global row 0..8191
    int br  = row >> 12;
    int t   = row & (L_ - 1);
    const float* wx = br ? wx1 : wx0;
    const float* wz = br ? wz1 : wz0;
    // per-channel taps (w[c][0..3] is exactly a float4)
    float4 wxv[4], wzv[4];
    #pragma unroll
    for (int k = 0; k < 4; k++) {
        wxv[k] = *(const float4*)(wx + (c4 + k) * 4);
        wzv[k] = *(const float4*)(wz + (c4 + k) * 4);
    }
    float4 ax = {0, 0, 0, 0}, az = {0, 0, 0, 0};
    #pragma unroll
    for (int j = 0; j < 4; j++) {
        int tt = t + j - 1;
        if (tt >= 0 && tt < L_) {
            const float* p = xz + (size_t)(row + j - 1) * 512;
            float4 vx = *(const float4*)(p + c4);
            float4 vz = *(const float4*)(p + 256 + c4);
            ax.x = fmaf(vx.x, ((const float*)&wxv[0])[j], ax.x);
            ax.y = fmaf(vx.y, ((const float*)&wxv[1])[j], ax.y);
            ax.z = fmaf(vx.z, ((const float*)&wxv[2])[j], ax.z);
            ax.w = fmaf(vx.w, ((const float*)&wxv[3])[j], ax.w);
            az.x = fmaf(vz.x, ((const float*)&wzv[0])[j], az.x);
            az.y = fmaf(vz.y, ((const float*)&wzv[1])[j], az.y);
            az.z = fmaf(vz.z, ((const float*)&wzv[2])[j], az.z);
            az.w = fmaf(vz.w, ((const float*)&wzv[3])[j], az.w);
        }
    }
    float4 sx, sz;
    sx.x = siluf(ax.x); sx.y = siluf(ax.y); sx.z = siluf(ax.z); sx.w = siluf(ax.w);
    sz.x = siluf(az.x); sz.y = siluf(az.y); sz.z = siluf(az.z); sz.w = siluf(az.w);
    *(float4*)(xs + (size_t)row * 256 + c4) = sx;
    ushort4 hx, lx, hz, lz;
    split2(sx.x, hx.x, lx.x); split2(sx.y, hx.y, lx.y);
    split2(sx.z, hx.z, lx.z); split2(sx.w, hx.w, lx.w);
    split2(sz.x, hz.x, lz.x); split2(sz.y, hz.y, lz.y);
    split2(sz.z, hz.z, lz.z); split2(sz.w, hz.w, lz.w);
    *(ushort4*)(xsh + (size_t)row * 256 + c4) = hx;
    *(ushort4*)(xsl + (size_t)row * 256 + c4) = lx;
    *(ushort4*)(yzh + (size_t)row * 512 + 256 + c4) = hz;
    *(ushort4*)(yzl + (size_t)row * 512 + 256 + c4) = lz;
}

// ---------------- fused dt_proj(K=32)+softplus+prep + shrinkpack ----------------
// grid (4, MROW/64). d-major outputs staged through LDS -> coalesced float4 stores.
__global__ __launch_bounds__(256) void dtprep_shrink(const float* __restrict__ A, int lda,
                                                     const float* __restrict__ W0,
                                                     const float* __restrict__ W1,
                                                     const float* __restrict__ b0,
                                                     const float* __restrict__ b1,
                                                     const float* __restrict__ xs,
                                                     const float* __restrict__ Dvec,
                                                     float* __restrict__ dtT,
                                                     float* __restrict__ duT,
                                                     float* __restrict__ udT,
                                                     const unsigned* __restrict__ bcmax,
                                                     float* __restrict__ Bs,
                                                     float* __restrict__ Cs) {
    __shared__ float As[16][68];
    __shared__ float Ws[16][68];
    __shared__ float tb[64 * 68];   // transpose buffer [n][m], stride 68 (16B-aligned rows)
    int tid = threadIdx.x;
    int kk = tid & 15;
    int rr = tid >> 4;
    int mblk = blockIdx.y * 64;
    int nblk = blockIdx.x * 64;
    int br = (mblk >= NROW) ? 1 : 0;
    const float* W    = br ? W1 : W0;
    const float* bias = br ? b1 : b0;
    float acc[4][4] = {};
    for (int k0 = 0; k0 < 32; k0 += 16) {
        #pragma unroll
        for (int j = 0; j < 4; j++) {
            As[kk][rr + 16 * j] = A[(size_t)(mblk + rr + 16 * j) * lda + k0 + kk];
        }
        #pragma unroll
        for (int j = 0; j < 4; j++) {
            Ws[kk][rr + 16 * j] = W[(size_t)(nblk + rr + 16 * j) * 32 + k0 + kk];
        }
        __syncthreads();
        int ty = tid >> 4;
        int tx = tid & 15;
        #pragma unroll
        for (int kq = 0; kq < 16; kq++) {
            float a0 = As[kq][ty * 4 + 0];
            float a1 = As[kq][ty * 4 + 1];
            float a2 = As[kq][ty * 4 + 2];
            float a3 = As[kq][ty * 4 + 3];
            float v0 = Ws[kq][tx * 4 + 0];
            float v1 = Ws[kq][tx * 4 + 1];
            float v2 = Ws[kq][tx * 4 + 2];
            float v3 = Ws[kq][tx * 4 + 3];
            acc[0][0] = fmaf(a0, v0, acc[0][0]); acc[0][1] = fmaf(a0, v1, acc[0][1]);
            acc[0][2] = fmaf(a0, v2, acc[0][2]); acc[0][3] = fmaf(a0, v3, acc[0][3]);
            acc[1][0] = fmaf(a1, v0, acc[1][0]); acc[1][1] = fmaf(a1, v1, acc[1][1]);
            acc[1][2] = fmaf(a1, v2, acc[1][2]); acc[1][3] = fmaf(a1, v3, acc[1][3]);
            acc[2][0] = fmaf(a2, v0, acc[2][0]); acc[2][1] = fmaf(a2, v1, acc[2][1]);
            acc[2][2] = fmaf(a2, v2, acc[2][2]); acc[2][3] = fmaf(a2, v3, acc[2][3]);
            acc[3][0] = fmaf(a3, v0, acc[3][0]); acc[3][1] = fmaf(a3, v1, acc[3][1]);
            acc[3][2] = fmaf(a3, v2, acc[3][2]); acc[3][3] = fmaf(a3, v3, acc[3][3]);
        }
        __syncthreads();
    }
    // epilogue: delta/u per (i,j); three d-major tensors via LDS transpose
    int ty = tid >> 4;
    int tx = tid & 15;
    float dlt[4][4], uu[4][4];
    #pragma unroll
    for (int i = 0; i < 4; i++) {
        int m = mblk + ty * 4 + i;
        #pragma unroll
        for (int j = 0; j < 4; j++) {
            int n = nblk + tx * 4 + j;
            dlt[i][j] = softplusf(acc[i][j] + bias[n]);
            uu[i][j]  = xs[(size_t)m * 256 + n];
        }
    }
    float Dv[4];
    #pragma unroll
    for (int j = 0; j < 4; j++) Dv[j] = Dvec[nblk + tx * 4 + j];

    int mlocbase = mblk & (NROW - 1);
    int nrd  = tid >> 2;              // 0..63: n-row to read
    int mc   = (tid & 3) * 4;         // starting float4 chunk
    size_t obase = ((size_t)br * 256 + nblk + nrd) * 4096 + mlocbase;
    #pragma unroll
    for (int pass = 0; pass < 3; pass++) {
        __syncthreads();   // WAR vs previous pass reads
        #pragma unroll
        for (int i = 0; i < 4; i++) {
            #pragma unroll
            for (int j = 0; j < 4; j++) {
                float v = (pass == 0) ? dlt[i][j] * LOG2E
                        : (pass == 1) ? dlt[i][j] * uu[i][j]
                                      : uu[i][j] * Dv[j];
                tb[(tx * 4 + j) * 68 + ty * 4 + i] = v;
            }
        }
        __syncthreads();
        float* dst = (pass == 0) ? dtT : (pass == 1) ? duT : udT;
        #pragma unroll
        for (int it = 0; it < 4; it++) {
            int cc = mc + it * 16;    // wait: cover 16 float4 chunks per n-row
            float4 v = *(const float4*)(tb + nrd * 68 + cc);
            *(float4*)(dst + obase + cc) = v;
        }
    }
    // ---- shrink slice: 64 rows x 64 cols of Bc or Cc ----
    {
        int q = blockIdx.x;
        int isC = q >> 1;
        int cbase = (q & 1) * 64;
        int xoff = isC ? (160 + cbase) : (32 + cbase);
        float thr = 0.1f * funkey(bcmax[2 * br + isC]);
        float* dstArr = isC ? Cs : Bs;
        int r = tid >> 2;
        int c0 = (tid & 3) * 16;
        const float* src = A + (size_t)(mblk + r) * lda + xoff + c0;
        float* dp = dstArr + (size_t)(mblk + r) * 128 + cbase + c0;
        #pragma unroll
        for (int i = 0; i < 16; i += 4) {
            float4 v = *(const float4*)(src + i);
            float4 o;
            o.x = shrinkf(v.x, thr);
            o.y = shrinkf(v.y, thr);
            o.z = shrinkf(v.z, thr);
            o.w = shrinkf(v.w, thr);
            *(float4*)(dp + i) = o;
        }
    }
}

// ---------------- scan pass 1: chunk-0 state summary (t 0..1023), barrier-free, no LDS ----------------
// h0 = 0, so chunk-1's start state is EXACTLY the chunk-0 recurrence result —
// same fma/exp2 sequence as the full serial scan -> bit-identical numerics.
// No y/reduce here (that happens in pass 2's chunk-0 blocks). Structure is
// scan10's inner loop minus red/barriers: depth-2 ring, incremental pointers,
// readlane dt/du broadcast (all proven codegen).
__global__ __launch_bounds__(128) void scan_pass1(float* __restrict__ ws,
                                                  const float* __restrict__ A_log,
                                                  const float* __restrict__ eps) {
    int blk  = blockIdx.x;
    int xcd  = blk & 7;
    int slot = blk >> 3;
    int combo = xcd >> 1;
    int d  = (xcd & 1) * 128 + slot;
    int br = combo >> 1;
    int b  = combo & 1;
    int tid = threadIdx.x;
    int lt  = tid & 63;

    float pv = ws[OFF_MINP + (tid & 31)];
    #pragma unroll
    for (int off = 16; off > 0; off >>= 1) pv = fminf(pv, __shfl_xor(pv, off));
    float e  = 1.0f + eps[0];
    float m1 = -e * __expf(pv);
    float t1 = 0.1f * m1;
    float t2 = 0.1f * shrinkf(m1, t1);
    float base = -e * __expf(A_log[d * 128 + tid]);
    float a = shrinkf(base, t1);
    if (br) a = shrinkf(a, t2);

    size_t dchain = ((size_t)br * 256 + d) * 4096 + (size_t)b * L_;
    const float* dtp = ws + OFF_DTT + dchain;
    const float* dup = ws + OFF_DUT + dchain;
    const float* Bq  = ws + OFF_BS + ((size_t)br * NROW + (size_t)b * L_) * 128 + tid;
    const float* Cq  = ws + OFF_CS + ((size_t)br * NROW + (size_t)b * L_) * 128 + tid;
    (void)Cq;

    float h = 0.0f;
    float Bb[2][8];
    #pragma unroll
    for (int j = 0; j < 8; j++) Bb[0][j] = Bq[j * 128];
    Bq += 1024;
    #pragma unroll
    for (int j = 0; j < 8; j++) Bb[1][j] = Bq[j * 128];
    Bq += 1024;

    float dt_c = dtp[lt];
    float du_c = dup[lt];
    float dt_n = 0.0f, du_n = 0.0f;

    for (int c = 0; c < 16; c++) {          // chunk 0 = 16 x 64 timesteps
        if (c < 15) { dt_n = dtp[64 + lt]; du_n = dup[64 + lt]; }
        dtp += 64; dup += 64;
        #pragma unroll
        for (int m = 0; m < 8; m++) {
            const int cur = m & 1;
            #pragma unroll
            for (int j = 0; j < 8; j++) {
                const int tl = m * 8 + j;
                float dt2 = rlanef(dt_c, tl);
                float du  = rlanef(du_c, tl);
                float ev = __builtin_amdgcn_exp2f(dt2 * a);
                h = fmaf(ev, h, du * Bb[cur][j]);
            }
            #pragma unroll
            for (int j = 0; j < 8; j++) Bb[cur][j] = Bq[j * 128];
            Bq += 1024;
        }
        dt_c = dt_n;
        du_c = du_n;
    }
    // h == reference h at t=1024 (bit-identical op sequence)
    ws[OFF_HIN + (((size_t)(br * 2 + b) * 256 + d) * 128 + tid)] = h;
}

// ---------------- scan pass 2: 2 paired d-chains x 1 chunk per block, 4 waves ----------------
// Occupancy lever (scan10 stuck at 2 waves/SIMD = VALUBusy 59%): chunk t in
// half (grid stays 1024 but blocks are 256-thr = 4 waves) and halve LDS via a
// 32-t reduce (red[2][32*132] ~ 34KB) -> 4 blocks/CU x 4 waves = 16 waves/CU
// = 4/SIMD. Pairing two d's (same (br,b) stream) in one block makes the
// second chain's B/C loads L1 hits -> per-XCD L2 traffic halves.
// Reduce geometry: lane l -> (t'=l>>1, q=l&1), each sums 32 cols of its
// wave's 64-col region; banks (4*(l>>1)+i)%32 = uniform 2-way (free, m136);
// pair-combine via shfl_xor(1); cross-half via comb (parity double-buffered).
__global__ __launch_bounds__(256) void scan_pass2(float* __restrict__ ws,
                                                  const float* __restrict__ A_log,
                                                  const float* __restrict__ eps) {
    int blk  = blockIdx.x;
    int xcd  = blk & 7;
    int slot = blk >> 3;          // 0..127
    int dhalf = xcd & 1;
    int combo = xcd >> 1;
    int br = combo >> 1;
    int b  = combo & 1;
    int chunk = slot >> 6;        // 0..1
    int pairIdx = slot & 63;
    int tid = threadIdx.x;        // 0..255
    int ch  = tid >> 7;           // chain-in-pair
    int nid = tid & 127;          // n within chain
    int lt  = tid & 63;
    int half = (tid >> 6) & 1;    // n-half within chain
    int d = dhalf * 128 + pairIdx * 2 + ch;

    float pv = ws[OFF_MINP + (tid & 31)];
    #pragma unroll
    for (int off = 16; off > 0; off >>= 1) pv = fminf(pv, __shfl_xor(pv, off));
    float e  = 1.0f + eps[0];
    float m1 = -e * __expf(pv);
    float t1 = 0.1f * m1;
    float t2 = 0.1f * shrinkf(m1, t1);
    float base = -e * __expf(A_log[d * 128 + nid]);
    float a = shrinkf(base, t1);
    if (br) a = shrinkf(a, t2);

    size_t dchain = ((size_t)br * 256 + d) * 4096 + (size_t)b * L_;
    size_t tb0 = (size_t)chunk * 1024;
    const float* dtp = ws + OFF_DTT + dchain + tb0;
    const float* dup = ws + OFF_DUT + dchain + tb0;
    const float* udp = ws + OFF_UDT + dchain + tb0;
    const float* Bq  = ws + OFF_BS + ((size_t)br * NROW + (size_t)b * L_ + tb0) * 128 + nid;
    const float* Cq  = ws + OFF_CS + ((size_t)br * NROW + (size_t)b * L_ + tb0) * 128 + nid;
    float*       yTp = ws + OFF_YT + dchain + tb0;

    // per-chain red: 32 t rows x 132 cols (wave-private 64-col halves + pad 4).
    __shared__ float red[2][32 * 132];
    __shared__ float comb[2][2][32];

    float h = 0.0f;
    if (chunk) h = ws[OFF_HIN + (((size_t)(br * 2 + b) * 256 + d) * 128 + nid)];

    float Bb[2][8], Cb[2][8];
    #pragma unroll
    for (int j = 0; j < 8; j++) { Bb[0][j] = Bq[j * 128]; Cb[0][j] = Cq[j * 128]; }
    Bq += 1024; Cq += 1024;
    #pragma unroll
    for (int j = 0; j < 8; j++) { Bb[1][j] = Bq[j * 128]; Cb[1][j] = Cq[j * 128]; }
    Bq += 1024; Cq += 1024;

    float dt_c = dtp[lt];
    float du_c = dup[lt];
    float dt_n = 0.0f, du_n = 0.0f;

    int tp = lt >> 1;             // reduce: timestep within 32-group
    int q  = lt & 1;              // reduce: column quarter (32 cols)

    for (int cc = 0; cc < 16; cc++) {       // 16 x 64 timesteps per chunk
        if (cc < 15) { dt_n = dtp[64 + lt]; du_n = dup[64 + lt]; }
        dtp += 64; dup += 64;
        #pragma unroll
        for (int g = 0; g < 2; g++) {       // two 32-t groups per cc
            float ud_c = udp[cc * 64 + g * 32 + tp];
            #pragma unroll
            for (int m = 0; m < 4; m++) {   // 4 phases of 8 steps
                const int cur = m & 1;
                #pragma unroll
                for (int j = 0; j < 8; j++) {
                    const int tl = g * 32 + m * 8 + j;   // readlane imm 0..63
                    const int tloc = m * 8 + j;          // red row 0..31
                    float dt2 = rlanef(dt_c, tl);
                    float du  = rlanef(du_c, tl);
                    float ev = __builtin_amdgcn_exp2f(dt2 * a);
                    h = fmaf(ev, h, du * Bb[cur][j]);
                    red[ch][tloc * 132 + half * 64 + lt] = h * Cb[cur][j];
                }
                #pragma unroll
                for (int j = 0; j < 8; j++) {
                    Bb[cur][j] = Bq[j * 128];
                    Cb[cur][j] = Cq[j * 128];
                }
                Bq += 1024; Cq += 1024;
            }
            // reduce 32 timesteps x this wave's 64 n-partials
            __builtin_amdgcn_wave_barrier();
            {
                const float* rp = &red[ch][tp * 132 + half * 64 + q * 32];
                float s0 = 0.f, s1 = 0.f, s2 = 0.f, s3 = 0.f;
                #pragma unroll
                for (int i = 0; i < 32; i += 4) {
                    float4 v = *(const float4*)(rp + i);
                    s0 += v.x; s1 += v.y; s2 += v.z; s3 += v.w;
                }
                float part = (s0 + s1) + (s2 + s3);
                float tot = part + __shfl_xor(part, 1);   // q0+q1 -> 64-col sum
                int par = (cc * 2 + g) & 1;
                if (half) comb[ch][par][tp] = tot;
                __syncthreads();              // one block barrier per 32 t
                if (half == 0 && q == 0)
                    yTp[cc * 64 + g * 32 + tp] = tot + comb[ch][par][tp] + ud_c;
            }
            __builtin_amdgcn_wave_barrier();
        }
        dt_c = dt_n;
        du_c = du_n;
    }
}

// ---------------- yT -> yz bf16 split (y half), merged: grid (8, 128, 2) ----------------
__global__ __launch_bounds__(256) void transpose_yz_kernel(const float* __restrict__ yT,
                                                           unsigned short* __restrict__ yzh,
                                                           unsigned short* __restrict__ yzl) {
    __shared__ float tile[32][33];
    int br = blockIdx.z;
    int m0 = blockIdx.x * 32;   // d rows
    int n0 = blockIdx.y * 32;   // within-branch t cols
    int tx = threadIdx.x;
    int ty = threadIdx.y;
    #pragma unroll
    for (int k = 0; k < 4; k++) {
        tile[ty + 8 * k][tx] = yT[((size_t)br * 256 + m0 + ty + 8 * k) * 4096 + n0 + tx];
    }
    __syncthreads();
    #pragma unroll
    for (int k = 0; k < 4; k++) {
        size_t dst = ((size_t)br * NROW + n0 + ty + 8 * k) * 512 + m0 + tx;
        unsigned short h, l;
        split2(tile[tx][ty + 8 * k], h, l);
        yzh[dst] = h; yzl[dst] = l;
    }
}

// ---------------- host-side launch ----------------
extern "C" void kernel_launch(void* const* d_in, const int* in_sizes, int n_in,
                              void* d_out, int out_size, void* d_ws, size_t ws_size,
                              hipStream_t stream) {
    const float* inp   = (const float*)d_in[0];
    const float* in_w[2]  = {(const float*)d_in[1],  (const float*)d_in[8]};
    const float* cxw[2]   = {(const float*)d_in[2],  (const float*)d_in[9]};
    const float* czw[2]   = {(const float*)d_in[3],  (const float*)d_in[10]};
    const float* xw[2]    = {(const float*)d_in[4],  (const float*)d_in[11]};
    const float* dtw[2]   = {(const float*)d_in[5],  (const float*)d_in[12]};
    const float* dtb[2]   = {(const float*)d_in[6],  (const float*)d_in[13]};
    const float* outw[2]  = {(const float*)d_in[7],  (const float*)d_in[14]};
    const float* A_log = (const float*)d_in[15];
    const float* Dvec  = (const float*)d_in[16];
    const float* eps   = (const float*)d_in[17];
    float* out = (float*)d_out;
    float* ws  = (float*)d_ws;
    unsigned short* hb = (unsigned short*)(ws + FLOAT_END);
    unsigned* bcmax = (unsigned*)(ws + OFF_BCMX);

    pre_all<<<PRE_BLOCKS, 256, 0, stream>>>(
        A_log, inp, in_w[0], in_w[1], outw[0], outw[1], xw[0], xw[1],
        ws, bcmax, hb);

    gemm_mfma<0, 0><<<dim3(512 / 64, MROW / 128), 256, 0, stream>>>(
        hb + HOFF_XINH, hb + HOFF_XINL, 512,
        hb + HOFF_INWH, hb + HOFF_INWL, WST_IN,
        ws + OFF_XZ, 512, 512, 512, nullptr);

    conv_silu_kernel<<<(MROW * 64) / 256, 256, 0, stream>>>(
        ws + OFF_XZ, ws + OFF_XS, hb + HOFF_XSH, hb + HOFF_XSL,
        hb + HOFF_YZH, hb + HOFF_YZL, cxw[0], cxw[1], czw[0], czw[1]);

    gemm_mfma<1, 1><<<dim3((288 + 63) / 64, MROW / 128), 256, 0, stream>>>(
        hb + HOFF_XSH, hb + HOFF_XSL, 256,
        hb + HOFF_XWH, hb + HOFF_XWL, WST_X,
        ws + OFF_XDBL, 288, 288, 256, bcmax);

    dtprep_shrink<<<dim3(4, MROW / 64), 256, 0, stream>>>(
        ws + OFF_XDBL, 288, dtw[0], dtw[1], dtb[0], dtb[1],
        ws + OFF_XS, Dvec,
        ws + OFF_DTT, ws + OFF_DUT, ws + OFF_UDT,
        bcmax, ws + OFF_BS, ws + OFF_CS);

    scan_pass1<<<dim3(1024), 128, 0, stream>>>(ws, A_log, eps);
    scan_pass2<<<dim3(1024), 256, 0, stream>>>(ws, A_log, eps);

    transpose_yz_kernel<<<dim3(256 / 32, NROW / 32, 2), dim3(32, 8), 0, stream>>>(
        ws + OFF_YT, hb + HOFF_YZH, hb + HOFF_YZL);

    gemm_mfma<0, 0><<<dim3(512 / 64, MROW / 128), 256, 0, stream>>>(
        hb + HOFF_YZH, hb + HOFF_YZL, 512,
        hb + HOFF_OUTWH, hb + HOFF_OUTWL, WST_IN,
        out, 512, 512, 512, nullptr);
}

// Round 10
// 313.630 us; speedup vs baseline: 1.1167x; 1.1167x over previous
//
#include <hip/hip_runtime.h>
#include <math.h>

// ---------------- problem constants ----------------
constexpr int B_    = 2;
constexpr int L_    = 2048;
constexpr int NROW  = B_ * L_;     // 4096 rows per branch
constexpr int MROW  = 2 * NROW;    // 8192 merged rows (branch-major)
constexpr int HALF_ = 256;
constexpr int DS_   = 128;

constexpr float LOG2E = 1.4426950408889634f;

// ---------------- ws layout ----------------
// fp32 region (float element offsets)
constexpr size_t OFF_MINP = 0;                                    // 32 (minA partials)
constexpr size_t OFF_BCMX = 32;                                   // 4 (uint atomics: brB,brC x2)
constexpr size_t OFF_XZ   = 64;                                   // 8192x512 (transient)
constexpr size_t OFF_YT   = OFF_XZ + (size_t)MROW * 256;          // alias: 2x256x4096 (after conv)
constexpr size_t OFF_XDBL = OFF_XZ + (size_t)MROW * 512;          // 8192x288
constexpr size_t OFF_XS   = OFF_XDBL + (size_t)MROW * 288;        // 8192x256
constexpr size_t OFF_BS   = OFF_XS  + (size_t)MROW * 256;         // 2 x 4096x128
constexpr size_t OFF_CS   = OFF_BS  + (size_t)2 * NROW * 128;     // 2 x 4096x128
constexpr size_t OFF_DTT  = OFF_CS  + (size_t)2 * NROW * 128;     // 2 x 256x4096
constexpr size_t OFF_DUT  = OFF_DTT + (size_t)2 * 256 * 4096;
constexpr size_t OFF_UDT  = OFF_DUT + (size_t)2 * 256 * 4096;
constexpr size_t FLOAT_END = OFF_UDT + (size_t)2 * 256 * 4096;

// bf16 region (ushort element offsets, based at ws + FLOAT_END floats)
constexpr size_t HOFF_XINH = 0;                                   // 8192x512
constexpr size_t HOFF_XINL = HOFF_XINH + (size_t)MROW * 512;
constexpr size_t HOFF_YZH  = HOFF_XINH;                           // alias (xin dead after in_proj)
constexpr size_t HOFF_YZL  = HOFF_XINL;
constexpr size_t HOFF_XSH  = HOFF_XINL + (size_t)MROW * 512;      // 8192x256
constexpr size_t HOFF_XSL  = HOFF_XSH  + (size_t)MROW * 256;
constexpr size_t HOFF_INWH = HOFF_XSL  + (size_t)MROW * 256;      // 2 x 512x512
constexpr size_t HOFF_INWL = HOFF_INWH + 524288;
constexpr size_t HOFF_XWH  = HOFF_INWL + 524288;                  // 2 x 288x256
constexpr size_t HOFF_XWL  = HOFF_XWH  + 147456;
constexpr size_t HOFF_OUTWH= HOFF_XWL  + 147456;                  // 2 x 512x512
constexpr size_t HOFF_OUTWL= HOFF_OUTWH+ 524288;

constexpr size_t WST_IN = 262144;   // per-branch in/out weight elems
constexpr size_t WST_X  = 73728;    // per-branch x_proj weight elems

// pre_all block ranges
constexpr int PRE_MINA = 32;
constexpr int PRE_WSPL = (1196032 + 255) / 256;   // 4672
constexpr int PRE_TIN  = 64 * 16 * 4;             // 4096
constexpr int PRE_BLOCKS = PRE_MINA + PRE_WSPL + PRE_TIN;

// ---------------- types / helpers ----------------
typedef __bf16 bf16x8 __attribute__((ext_vector_type(8)));
typedef float  f32x4  __attribute__((ext_vector_type(4)));

__device__ __forceinline__ unsigned short bf16rn(float x) {
    unsigned u = __float_as_uint(x);
    unsigned r = (u + 0x7FFFu + ((u >> 16) & 1u)) >> 16;
    return (unsigned short)r;
}
__device__ __forceinline__ void split2(float x, unsigned short& h, unsigned short& l) {
    h = bf16rn(x);
    float hf = __uint_as_float(((unsigned)h) << 16);
    l = bf16rn(x - hf);
}

__device__ __forceinline__ float shrinkf(float v, float thr) {
    float a = fabsf(v) - thr;
    a = fmaxf(a, 0.0f);
    float r = copysignf(a, v);
    return (v == 0.0f) ? 0.0f : r;
}
__device__ __forceinline__ float siluf(float v) { return v / (1.0f + __expf(-v)); }
__device__ __forceinline__ float softplusf(float v) {
    return fmaxf(v, 0.0f) + log1pf(__expf(-fabsf(v)));
}
__device__ __forceinline__ float rlanef(float v, int l) {
    return __int_as_float(__builtin_amdgcn_readlane(__float_as_int(v), l));
}
// monotone float<->uint key for atomicMax on signed floats
__device__ __forceinline__ unsigned fkey(float f) {
    unsigned u = __float_as_uint(f);
    return (u >> 31) ? ~u : (u | 0x80000000u);
}
__device__ __forceinline__ float funkey(unsigned k) {
    unsigned u = (k >> 31) ? (k & 0x7FFFFFFFu) : ~k;
    return __uint_as_float(u);
}

// ---------------- pre_all: minA + weight splits + input transpose, one dispatch ----------------
__global__ __launch_bounds__(256) void pre_all(const float* __restrict__ A_log,
                                               const float* __restrict__ inp,
                                               const float* __restrict__ in_w0,
                                               const float* __restrict__ in_w1,
                                               const float* __restrict__ outw0,
                                               const float* __restrict__ outw1,
                                               const float* __restrict__ xw0,
                                               const float* __restrict__ xw1,
                                               float* __restrict__ ws,
                                               unsigned* __restrict__ bcmax,
                                               unsigned short* __restrict__ hb) {
    int bid = blockIdx.x;
    int tid = threadIdx.x;
    if (bid < PRE_MINA) {
        // ---- minA role ----
        __shared__ float sbuf[8];
        int i = bid * 1024 + tid * 4;
        float4 v = *(const float4*)(A_log + i);
        float mv = fminf(fminf(v.x, v.y), fminf(v.z, v.w));
        #pragma unroll
        for (int off = 32; off > 0; off >>= 1) mv = fminf(mv, __shfl_xor(mv, off));
        if ((tid & 63) == 0) sbuf[tid >> 6] = mv;
        __syncthreads();
        if (tid == 0) {
            float r = fminf(fminf(sbuf[0], sbuf[1]), fminf(sbuf[2], sbuf[3]));
            ws[OFF_MINP + bid] = r;
        }
        if (bid == 0 && tid < 4) bcmax[tid] = 0u;
    } else if (bid < PRE_MINA + PRE_WSPL) {
        // ---- wsplit role ----
        int i = (bid - PRE_MINA) * 256 + tid;
        if (i >= 1196032) return;
        const float* src;
        size_t hbase, lbase;
        int off;
        if (i < 1048576) {
            int t = i >> 18;
            off = i & 262143;
            src = (t == 0) ? in_w0 : (t == 1) ? in_w1 : (t == 2) ? outw0 : outw1;
            if (t < 2) { hbase = HOFF_INWH + (size_t)t * WST_IN;  lbase = HOFF_INWL + (size_t)t * WST_IN; }
            else       { hbase = HOFF_OUTWH + (size_t)(t - 2) * WST_IN; lbase = HOFF_OUTWL + (size_t)(t - 2) * WST_IN; }
        } else {
            int j = i - 1048576;
            int t = (j < (int)WST_X) ? 0 : 1;
            off = j - t * (int)WST_X;
            src = t ? xw1 : xw0;
            hbase = HOFF_XWH + (size_t)t * WST_X;
            lbase = HOFF_XWL + (size_t)t * WST_X;
        }
        unsigned short h, l;
        split2(src[off], h, l);
        hb[hbase + off] = h;
        hb[lbase + off] = l;
    } else {
        // ---- transpose_in role ----
        __shared__ float tile[32][33];
        int idx = bid - PRE_MINA - PRE_WSPL;    // 0..4095
        int bx = idx & 63;          // t block (64)
        int by = (idx >> 6) & 15;   // ch block (16)
        int z  = idx >> 10;         // 0..3
        int br = z >> 1;
        int b  = z & 1;
        int t0 = bx * 32;
        int m0 = by * 32;
        int tx = tid & 31;
        int ty = tid >> 5;
        #pragma unroll
        for (int k = 0; k < 4; k++) {
            tile[ty + 8 * k][tx] =
                inp[((size_t)b * 1024 + br * 512 + m0 + ty + 8 * k) * L_ + t0 + tx];
        }
        __syncthreads();
        #pragma unroll
        for (int k = 0; k < 4; k++) {
            size_t dst = ((size_t)br * NROW + (size_t)b * L_ + t0 + ty + 8 * k) * 512 + m0 + tx;
            unsigned short h, l;
            split2(tile[tx][ty + 8 * k], h, l);
            hb[HOFF_XINH + dst] = h;
            hb[HOFF_XINL + dst] = l;
        }
    }
}

// ---------------- MFMA GEMM (bf16x3), 128x128 tile ----------------
// N-tile 64 -> 128. Per k-step: 48 MFMA vs 8 staging loads + 8 LDS stores
// (was 24 vs 6+6) -> 1.5x better amortization; B's LDS-stage traffic per
// output halves; block count halves. LDS = 4x128x40x2B = 40960 B = exactly
// 4 blocks/CU (16 waves/CU). K-summation order per output column is UNCHANGED
// -> bit-identical results. DOMAX 16-col group classification and NGUARD
// row/col guards carry over (x_proj grid.x = 3, guarded rows load 0).
template <int NGUARD, int DOMAX>
__global__ __launch_bounds__(256) void gemm_mfma(const unsigned short* __restrict__ Ah,
                                                 const unsigned short* __restrict__ Al, int lda,
                                                 const unsigned short* __restrict__ WhB,
                                                 const unsigned short* __restrict__ WlB,
                                                 size_t wstride,
                                                 float* __restrict__ C, int ldc,
                                                 int N, int K,
                                                 unsigned* __restrict__ bcmax) {
    __shared__ __align__(16) unsigned short sAh[128 * 40];
    __shared__ __align__(16) unsigned short sAl[128 * 40];
    __shared__ __align__(16) unsigned short sBh[128 * 40];
    __shared__ __align__(16) unsigned short sBl[128 * 40];
    int tid  = threadIdx.x;
    int wid  = tid >> 6;
    int lane = tid & 63;
    int fr   = lane & 15;
    int kg   = lane >> 4;
    int mblk = blockIdx.y * 128;
    int nblk = blockIdx.x * 128;
    int br   = (mblk >= NROW) ? 1 : 0;
    const unsigned short* Wh = WhB + (size_t)br * wstride;
    const unsigned short* Wl = WlB + (size_t)br * wstride;
    int srow = tid >> 2;            // 0..63
    int skp  = (tid & 3) * 8;       // k-chunk of 8
    bool brow_ok0 = (!NGUARD) || ((nblk + srow) < N);
    bool brow_ok1 = (!NGUARD) || ((nblk + 64 + srow) < N);

    const unsigned short* pA0 = Ah + (size_t)(mblk + srow) * lda + skp;
    const unsigned short* pA1 = Ah + (size_t)(mblk + 64 + srow) * lda + skp;
    const unsigned short* pL0 = Al + (size_t)(mblk + srow) * lda + skp;
    const unsigned short* pL1 = Al + (size_t)(mblk + 64 + srow) * lda + skp;
    const unsigned short* pB0h = Wh + (size_t)(nblk + srow) * K + skp;
    const unsigned short* pB1h = Wh + (size_t)(nblk + 64 + srow) * K + skp;
    const unsigned short* pB0l = Wl + (size_t)(nblk + srow) * K + skp;
    const unsigned short* pB1l = Wl + (size_t)(nblk + 64 + srow) * K + skp;

    f32x4 acc[2][8] = {};

    uint4 rah0 = *(const uint4*)(pA0);
    uint4 rah1 = *(const uint4*)(pA1);
    uint4 ral0 = *(const uint4*)(pL0);
    uint4 ral1 = *(const uint4*)(pL1);
    uint4 rbh0 = {0, 0, 0, 0}, rbh1 = {0, 0, 0, 0};
    uint4 rbl0 = {0, 0, 0, 0}, rbl1 = {0, 0, 0, 0};
    if (brow_ok0) { rbh0 = *(const uint4*)(pB0h); rbl0 = *(const uint4*)(pB0l); }
    if (brow_ok1) { rbh1 = *(const uint4*)(pB1h); rbl1 = *(const uint4*)(pB1l); }

    for (int k0 = 0; k0 < K; k0 += 32) {
        __syncthreads();   // WAR vs previous iter's ds_reads
        *(uint4*)(sAh + srow * 40 + skp) = rah0;
        *(uint4*)(sAh + (64 + srow) * 40 + skp) = rah1;
        *(uint4*)(sAl + srow * 40 + skp) = ral0;
        *(uint4*)(sAl + (64 + srow) * 40 + skp) = ral1;
        *(uint4*)(sBh + srow * 40 + skp) = rbh0;
        *(uint4*)(sBh + (64 + srow) * 40 + skp) = rbh1;
        *(uint4*)(sBl + srow * 40 + skp) = rbl0;
        *(uint4*)(sBl + (64 + srow) * 40 + skp) = rbl1;
        __syncthreads();

        int kn = k0 + 32;
        if (kn < K) {      // prefetch next chunk; latency hides under MFMAs below
            rah0 = *(const uint4*)(pA0 + kn);
            rah1 = *(const uint4*)(pA1 + kn);
            ral0 = *(const uint4*)(pL0 + kn);
            ral1 = *(const uint4*)(pL1 + kn);
            if (brow_ok0) { rbh0 = *(const uint4*)(pB0h + kn); rbl0 = *(const uint4*)(pB0l + kn); }
            if (brow_ok1) { rbh1 = *(const uint4*)(pB1h + kn); rbl1 = *(const uint4*)(pB1l + kn); }
        }

        bf16x8 ah0 = *(const bf16x8*)(sAh + (wid * 32 + fr) * 40 + kg * 8);
        bf16x8 ah1 = *(const bf16x8*)(sAh + (wid * 32 + 16 + fr) * 40 + kg * 8);
        bf16x8 al0 = *(const bf16x8*)(sAl + (wid * 32 + fr) * 40 + kg * 8);
        bf16x8 al1 = *(const bf16x8*)(sAl + (wid * 32 + 16 + fr) * 40 + kg * 8);
        #pragma unroll
        for (int nt = 0; nt < 8; nt++) {
            bf16x8 bh = *(const bf16x8*)(sBh + (nt * 16 + fr) * 40 + kg * 8);
            bf16x8 bl = *(const bf16x8*)(sBl + (nt * 16 + fr) * 40 + kg * 8);
            acc[0][nt] = __builtin_amdgcn_mfma_f32_16x16x32_bf16(ah0, bh, acc[0][nt], 0, 0, 0);
            acc[0][nt] = __builtin_amdgcn_mfma_f32_16x16x32_bf16(ah0, bl, acc[0][nt], 0, 0, 0);
            acc[0][nt] = __builtin_amdgcn_mfma_f32_16x16x32_bf16(al0, bh, acc[0][nt], 0, 0, 0);
            acc[1][nt] = __builtin_amdgcn_mfma_f32_16x16x32_bf16(ah1, bh, acc[1][nt], 0, 0, 0);
            acc[1][nt] = __builtin_amdgcn_mfma_f32_16x16x32_bf16(ah1, bl, acc[1][nt], 0, 0, 0);
            acc[1][nt] = __builtin_amdgcn_mfma_f32_16x16x32_bf16(al1, bh, acc[1][nt], 0, 0, 0);
        }
    }
    // C/D layout: col = lane&15, row = (lane>>4)*4 + reg
    #pragma unroll
    for (int mt = 0; mt < 2; mt++) {
        #pragma unroll
        for (int nt = 0; nt < 8; nt++) {
            int col = nblk + nt * 16 + fr;
            if (NGUARD && col >= N) continue;
            #pragma unroll
            for (int r = 0; r < 4; r++) {
                int row = mblk + wid * 32 + mt * 16 + kg * 4 + r;
                C[(size_t)row * ldc + col] = acc[mt][nt][r];
            }
        }
    }
    if (DOMAX) {
        float mb = -INFINITY, mc = -INFINITY;
        #pragma unroll
        for (int nt = 0; nt < 8; nt++) {
            int c16 = nblk + nt * 16;
            if (c16 >= 32 && c16 < 160) {
                #pragma unroll
                for (int mt = 0; mt < 2; mt++)
                    #pragma unroll
                    for (int r = 0; r < 4; r++) mb = fmaxf(mb, acc[mt][nt][r]);
            } else if (c16 >= 160 && c16 < 288) {
                #pragma unroll
                for (int mt = 0; mt < 2; mt++)
                    #pragma unroll
                    for (int r = 0; r < 4; r++) mc = fmaxf(mc, acc[mt][nt][r]);
            }
        }
        #pragma unroll
        for (int off = 32; off > 0; off >>= 1) {
            mb = fmaxf(mb, __shfl_xor(mb, off));
            mc = fmaxf(mc, __shfl_xor(mc, off));
        }
        if (lane == 0) {
            if (mb > -INFINITY) atomicMax(bcmax + 2 * br,     fkey(mb));
            if (mc > -INFINITY) atomicMax(bcmax + 2 * br + 1, fkey(mc));
        }
    }
}

// ---------------- depthwise conv (k=4) + SiLU, vectorized 4 channels/thread ----------------
__global__ __launch_bounds__(256) void conv_silu_kernel(const float* __restrict__ xz,
                                                        float* __restrict__ xs,
                                                        unsigned short* __restrict__ xsh,
                                                        unsigned short* __restrict__ xsl,
                                                        unsigned short* __restrict__ yzh,
                                                        unsigned short* __restrict__ yzl,
                                                        const float* __restrict__ wx0,
                                                        const float* __restrict__ wx1,
                                                        const float* __restrict__ wz0,
                                                        const float* __restrict__ wz1) {
    int gid = blockIdx.x * 256 + threadIdx.x;   // over MROW*64
    int c4  = (gid & 63) << 2;                  // channel quad
    int row = gid >> 6;                         // global row 0..8191
    int br  = row >> 12;
    int t   = row & (L_ - 1);
    const float* wx = br ? wx1 : wx0;
    const float* wz = br ? wz1 : wz0;
    // per-channel taps (w[c][0..3] is exactly a float4)
    float4 wxv[4], wzv[4];
    #pragma unroll
    for (int k = 0; k < 4; k++) {
        wxv[k] = *(const float4*)(wx + (c4 + k) * 4);
        wzv[k] = *(const float4*)(wz + (c4 + k) * 4);
    }
    float4 ax = {0, 0, 0, 0}, az = {0, 0, 0, 0};
    #pragma unroll
    for (int j = 0; j < 4; j++) {
        int tt = t + j - 1;
        if (tt >= 0 && tt < L_) {
            const float* p = xz + (size_t)(row + j - 1) * 512;
            float4 vx = *(const float4*)(p + c4);
            float4 vz = *(const float4*)(p + 256 + c4);
            ax.x = fmaf(vx.x, ((const float*)&wxv[0])[j], ax.x);
            ax.y = fmaf(vx.y, ((const float*)&wxv[1])[j], ax.y);
            ax.z = fmaf(vx.z, ((const float*)&wxv[2])[j], ax.z);
            ax.w = fmaf(vx.w, ((const float*)&wxv[3])[j], ax.w);
            az.x = fmaf(vz.x, ((const float*)&wzv[0])[j], az.x);
            az.y = fmaf(vz.y, ((const float*)&wzv[1])[j], az.y);
            az.z = fmaf(vz.z, ((const float*)&wzv[2])[j], az.z);
            az.w = fmaf(vz.w, ((const float*)&wzv[3])[j], az.w);
        }
    }
    float4 sx, sz;
    sx.x = siluf(ax.x); sx.y = siluf(ax.y); sx.z = siluf(ax.z); sx.w = siluf(ax.w);
    sz.x = siluf(az.x); sz.y = siluf(az.y); sz.z = siluf(az.z); sz.w = siluf(az.w);
    *(float4*)(xs + (size_t)row * 256 + c4) = sx;
    ushort4 hx, lx, hz, lz;
    split2(sx.x, hx.x, lx.x); split2(sx.y, hx.y, lx.y);
    split2(sx.z, hx.z, lx.z); split2(sx.w, hx.w, lx.w);
    split2(sz.x, hz.x, lz.x); split2(sz.y, hz.y, lz.y);
    split2(sz.z, hz.z, lz.z); split2(sz.w, hz.w, lz.w);
    *(ushort4*)(xsh + (size_t)row * 256 + c4) = hx;
    *(ushort4*)(xsl + (size_t)row * 256 + c4) = lx;
    *(ushort4*)(yzh + (size_t)row * 512 + 256 + c4) = hz;
    *(ushort4*)(yzl + (size_t)row * 512 + 256 + c4) = lz;
}

// ---------------- fused dt_proj(K=32)+softplus+prep + shrinkpack ----------------
// grid (4, MROW/64). d-major outputs staged through LDS -> coalesced float4 stores.
__global__ __launch_bounds__(256) void dtprep_shrink(const float* __restrict__ A, int lda,
                                                     const float* __restrict__ W0,
                                                     const float* __restrict__ W1,
                                                     const float* __restrict__ b0,
                                                     const float* __restrict__ b1,
                                                     const float* __restrict__ xs,
                                                     const float* __restrict__ Dvec,
                                                     float* __restrict__ dtT,
                                                     float* __restrict__ duT,
                                                     float* __restrict__ udT,
                                                     const unsigned* __restrict__ bcmax,
                                                     float* __restrict__ Bs,
                                                     float* __restrict__ Cs) {
    __shared__ float As[16][68];
    __shared__ float Ws[16][68];
    __shared__ float tb[64 * 68];   // transpose buffer [n][m], stride 68 (16B-aligned rows)
    int tid = threadIdx.x;
    int kk = tid & 15;
    int rr = tid >> 4;
    int mblk = blockIdx.y * 64;
    int nblk = blockIdx.x * 64;
    int br = (mblk >= NROW) ? 1 : 0;
    const float* W    = br ? W1 : W0;
    const float* bias = br ? b1 : b0;
    float acc[4][4] = {};
    for (int k0 = 0; k0 < 32; k0 += 16) {
        #pragma unroll
        for (int j = 0; j < 4; j++) {
            As[kk][rr + 16 * j] = A[(size_t)(mblk + rr + 16 * j) * lda + k0 + kk];
        }
        #pragma unroll
        for (int j = 0; j < 4; j++) {
            Ws[kk][rr + 16 * j] = W[(size_t)(nblk + rr + 16 * j) * 32 + k0 + kk];
        }
        __syncthreads();
        int ty = tid >> 4;
        int tx = tid & 15;
        #pragma unroll
        for (int kq = 0; kq < 16; kq++) {
            float a0 = As[kq][ty * 4 + 0];
            float a1 = As[kq][ty * 4 + 1];
            float a2 = As[kq][ty * 4 + 2];
            float a3 = As[kq][ty * 4 + 3];
            float v0 = Ws[kq][tx * 4 + 0];
            float v1 = Ws[kq][tx * 4 + 1];
            float v2 = Ws[kq][tx * 4 + 2];
            float v3 = Ws[kq][tx * 4 + 3];
            acc[0][0] = fmaf(a0, v0, acc[0][0]); acc[0][1] = fmaf(a0, v1, acc[0][1]);
            acc[0][2] = fmaf(a0, v2, acc[0][2]); acc[0][3] = fmaf(a0, v3, acc[0][3]);
            acc[1][0] = fmaf(a1, v0, acc[1][0]); acc[1][1] = fmaf(a1, v1, acc[1][1]);
            acc[1][2] = fmaf(a1, v2, acc[1][2]); acc[1][3] = fmaf(a1, v3, acc[1][3]);
            acc[2][0] = fmaf(a2, v0, acc[2][0]); acc[2][1] = fmaf(a2, v1, acc[2][1]);
            acc[2][2] = fmaf(a2, v2, acc[2][2]); acc[2][3] = fmaf(a2, v3, acc[2][3]);
            acc[3][0] = fmaf(a3, v0, acc[3][0]); acc[3][1] = fmaf(a3, v1, acc[3][1]);
            acc[3][2] = fmaf(a3, v2, acc[3][2]); acc[3][3] = fmaf(a3, v3, acc[3][3]);
        }
        __syncthreads();
    }
    // epilogue: delta/u per (i,j); three d-major tensors via LDS transpose
    int ty = tid >> 4;
    int tx = tid & 15;
    float dlt[4][4], uu[4][4];
    #pragma unroll
    for (int i = 0; i < 4; i++) {
        int m = mblk + ty * 4 + i;
        #pragma unroll
        for (int j = 0; j < 4; j++) {
            int n = nblk + tx * 4 + j;
            dlt[i][j] = softplusf(acc[i][j] + bias[n]);
            uu[i][j]  = xs[(size_t)m * 256 + n];
        }
    }
    float Dv[4];
    #pragma unroll
    for (int j = 0; j < 4; j++) Dv[j] = Dvec[nblk + tx * 4 + j];

    int mlocbase = mblk & (NROW - 1);
    int nrd  = tid >> 2;              // 0..63: n-row to read
    int mc   = (tid & 3) * 4;         // starting float4 chunk
    size_t obase = ((size_t)br * 256 + nblk + nrd) * 4096 + mlocbase;
    #pragma unroll
    for (int pass = 0; pass < 3; pass++) {
        __syncthreads();   // WAR vs previous pass reads
        #pragma unroll
        for (int i = 0; i < 4; i++) {
            #pragma unroll
            for (int j = 0; j < 4; j++) {
                float v = (pass == 0) ? dlt[i][j] * LOG2E
                        : (pass == 1) ? dlt[i][j] * uu[i][j]
                                      : uu[i][j] * Dv[j];
                tb[(tx * 4 + j) * 68 + ty * 4 + i] = v;
            }
        }
        __syncthreads();
        float* dst = (pass == 0) ? dtT : (pass == 1) ? duT : udT;
        #pragma unroll
        for (int it = 0; it < 4; it++) {
            int cc = mc + it * 16;    // wait: cover 16 float4 chunks per n-row
            float4 v = *(const float4*)(tb + nrd * 68 + cc);
            *(float4*)(dst + obase + cc) = v;
        }
    }
    // ---- shrink slice: 64 rows x 64 cols of Bc or Cc ----
    {
        int q = blockIdx.x;
        int isC = q >> 1;
        int cbase = (q & 1) * 64;
        int xoff = isC ? (160 + cbase) : (32 + cbase);
        float thr = 0.1f * funkey(bcmax[2 * br + isC]);
        float* dstArr = isC ? Cs : Bs;
        int r = tid >> 2;
        int c0 = (tid & 3) * 16;
        const float* src = A + (size_t)(mblk + r) * lda + xoff + c0;
        float* dp = dstArr + (size_t)(mblk + r) * 128 + cbase + c0;
        #pragma unroll
        for (int i = 0; i < 16; i += 4) {
            float4 v = *(const float4*)(src + i);
            float4 o;
            o.x = shrinkf(v.x, thr);
            o.y = shrinkf(v.y, thr);
            o.z = shrinkf(v.z, thr);
            o.w = shrinkf(v.w, thr);
            *(float4*)(dp + i) = o;
        }
    }
}

// ---------------- selective scan v10 (proven 121.3us): scan9 + incremental B/C pointers ----------------
// Round-7 chunking post-mortem: pass2's aggregate VALU work (72us) equals
// scan10's (71us) — the scan is VALU-ISSUE-BOUND at this instruction count;
// occupancy levers only trim stall, and pass1's redundant recurrence (+41us)
// exceeds that. scan10 is the floor for this structure -> restored verbatim.
__global__ __launch_bounds__(128) void scan10_kernel(float* __restrict__ ws,
                                                     const float* __restrict__ A_log,
                                                     const float* __restrict__ eps) {
    int blk  = blockIdx.x;
    int xcd  = blk & 7;
    int slot = blk >> 3;
    int combo = xcd >> 1;
    int d  = (xcd & 1) * 128 + slot;
    int br = combo >> 1;
    int b  = combo & 1;
    int tid = threadIdx.x;
    int lt  = tid & 63;
    int half = tid >> 6;

    float pv = ws[OFF_MINP + (tid & 31)];
    #pragma unroll
    for (int off = 16; off > 0; off >>= 1) pv = fminf(pv, __shfl_xor(pv, off));
    float e  = 1.0f + eps[0];
    float m1 = -e * __expf(pv);
    float t1 = 0.1f * m1;
    float t2 = 0.1f * shrinkf(m1, t1);
    float base = -e * __expf(A_log[d * 128 + tid]);
    float a = shrinkf(base, t1);
    if (br) a = shrinkf(a, t2);

    size_t dchain = ((size_t)br * 256 + d) * 4096 + (size_t)b * L_;
    const float* dtp = ws + OFF_DTT + dchain;
    const float* dup = ws + OFF_DUT + dchain;
    const float* udp = ws + OFF_UDT + dchain;
    const float* Bq  = ws + OFF_BS + ((size_t)br * NROW + (size_t)b * L_) * 128 + tid;
    const float* Cq  = ws + OFF_CS + ((size_t)br * NROW + (size_t)b * L_) * 128 + tid;
    float*       yTp = ws + OFF_YT + dchain;

    // red: 64 timesteps x [wave0 cols 0..63 | wave1 cols 64..127 | pad 4].
    // Row stride 132 == 4 (mod 32): float4 reads have octet starting banks
    // {0,4,...,28} -> perfect 32-bank partition per 8 lanes -> conflict-free
    // (measured 0 in scan3/scan8/scan9/scan10). Writes lane-consecutive -> free.
    __shared__ float red[64 * 132];
    __shared__ float comb[2][64];

    float h = 0.0f;

    // depth-2 ring; Bq/Cq always point at the NEXT phase to fetch.
    float Bb[2][8], Cb[2][8];
    #pragma unroll
    for (int j = 0; j < 8; j++) { Bb[0][j] = Bq[j * 128]; Cb[0][j] = Cq[j * 128]; }
    Bq += 1024; Cq += 1024;
    #pragma unroll
    for (int j = 0; j < 8; j++) { Bb[1][j] = Bq[j * 128]; Cb[1][j] = Cq[j * 128]; }
    Bq += 1024; Cq += 1024;

    // per-lane dt/du (lane lt holds timestep lt of current c), prefetched 1 c ahead
    float dt_c = dtp[lt];
    float du_c = dup[lt];
    float dt_n = 0.0f, du_n = 0.0f;

    for (int c = 0; c < 32; c++) {
        if (c < 31) { dt_n = dtp[64 + lt]; du_n = dup[64 + lt]; }
        dtp += 64; dup += 64;
        // u*D for this c's 64 timesteps (branchless; wave1's value unused);
        // issued here, consumed at end of c -> full-c slack, vmcnt-counted.
        float ud_c = udp[c * 64 + lt];
        #pragma unroll
        for (int m = 0; m < 8; m++) {
            const int cur = m & 1;
            #pragma unroll
            for (int j = 0; j < 8; j++) {
                const int tl = m * 8 + j;              // readlane imm
                float dt2 = rlanef(dt_c, tl);
                float du  = rlanef(du_c, tl);
                float ev = __builtin_amdgcn_exp2f(dt2 * a);
                h = fmaf(ev, h, du * Bb[cur][j]);
                red[tl * 132 + half * 64 + lt] = h * Cb[cur][j];
            }
            // prefetch phase G+2 (unconditional; tail over-read is safe junk)
            #pragma unroll
            for (int j = 0; j < 8; j++) {
                Bb[cur][j] = Bq[j * 128];
                Cb[cur][j] = Cq[j * 128];
            }
            Bq += 1024; Cq += 1024;
        }
        // wave-private reduce: lane lt sums its wave's 64 n-partials of
        // timestep lt (float4 at row stride 132 -> conflict-free).
        __builtin_amdgcn_wave_barrier();   // keep reads after this wave's writes
        {
            const float* rp = &red[lt * 132 + half * 64];
            float s0 = 0.f, s1 = 0.f, s2 = 0.f, s3 = 0.f;
            #pragma unroll
            for (int i = 0; i < 64; i += 4) {
                float4 v = *(const float4*)(rp + i);
                s0 += v.x; s1 += v.y; s2 += v.z; s3 += v.w;
            }
            float part = (s0 + s1) + (s2 + s3);
            if (half) comb[c & 1][lt] = part;
            __syncthreads();               // the ONLY block barrier per c
            if (!half) yTp[c * 64 + lt] = part + comb[c & 1][lt] + ud_c;
        }
        __builtin_amdgcn_wave_barrier();   // keep next c's writes after reads
        dt_c = dt_n;
        du_c = du_n;
    }
}

// ---------------- yT -> yz bf16 split (y half), merged: grid (8, 128, 2) ----------------
__global__ __launch_bounds__(256) void transpose_yz_kernel(const float* __restrict__ yT,
                                                           unsigned short* __restrict__ yzh,
                                                           unsigned short* __restrict__ yzl) {
    __shared__ float tile[32][33];
    int br = blockIdx.z;
    int m0 = blockIdx.x * 32;   // d rows
    int n0 = blockIdx.y * 32;   // within-branch t cols
    int tx = threadIdx.x;
    int ty = threadIdx.y;
    #pragma unroll
    for (int k = 0; k < 4; k++) {
        tile[ty + 8 * k][tx] = yT[((size_t)br * 256 + m0 + ty + 8 * k) * 4096 + n0 + tx];
    }
    __syncthreads();
    #pragma unroll
    for (int k = 0; k < 4; k++) {
        size_t dst = ((size_t)br * NROW + n0 + ty + 8 * k) * 512 + m0 + tx;
        unsigned short h, l;
        split2(tile[tx][ty + 8 * k], h, l);
        yzh[dst] = h; yzl[dst] = l;
    }
}

// ---------------- host-side launch ----------------
extern "C" void kernel_launch(void* const* d_in, const int* in_sizes, int n_in,
                              void* d_out, int out_size, void* d_ws, size_t ws_size,
                              hipStream_t stream) {
    const float* inp   = (const float*)d_in[0];
    const float* in_w[2]  = {(const float*)d_in[1],  (const float*)d_in[8]};
    const float* cxw[2]   = {(const float*)d_in[2],  (const float*)d_in[9]};
    const float* czw[2]   = {(const float*)d_in[3],  (const float*)d_in[10]};
    const float* xw[2]    = {(const float*)d_in[4],  (const float*)d_in[11]};
    const float* dtw[2]   = {(const float*)d_in[5],  (const float*)d_in[12]};
    const float* dtb[2]   = {(const float*)d_in[6],  (const float*)d_in[13]};
    const float* outw[2]  = {(const float*)d_in[7],  (const float*)d_in[14]};
    const float* A_log = (const float*)d_in[15];
    const float* Dvec  = (const float*)d_in[16];
    const float* eps   = (const float*)d_in[17];
    float* out = (float*)d_out;
    float* ws  = (float*)d_ws;
    unsigned short* hb = (unsigned short*)(ws + FLOAT_END);
    unsigned* bcmax = (unsigned*)(ws + OFF_BCMX);

    pre_all<<<PRE_BLOCKS, 256, 0, stream>>>(
        A_log, inp, in_w[0], in_w[1], outw[0], outw[1], xw[0], xw[1],
        ws, bcmax, hb);

    gemm_mfma<0, 0><<<dim3(512 / 128, MROW / 128), 256, 0, stream>>>(
        hb + HOFF_XINH, hb + HOFF_XINL, 512,
        hb + HOFF_INWH, hb + HOFF_INWL, WST_IN,
        ws + OFF_XZ, 512, 512, 512, nullptr);

    conv_silu_kernel<<<(MROW * 64) / 256, 256, 0, stream>>>(
        ws + OFF_XZ, ws + OFF_XS, hb + HOFF_XSH, hb + HOFF_XSL,
        hb + HOFF_YZH, hb + HOFF_YZL, cxw[0], cxw[1], czw[0], czw[1]);

    gemm_mfma<1, 1><<<dim3((288 + 127) / 128, MROW / 128), 256, 0, stream>>>(
        hb + HOFF_XSH, hb + HOFF_XSL, 256,
        hb + HOFF_XWH, hb + HOFF_XWL, WST_X,
        ws + OFF_XDBL, 288, 288, 256, bcmax);

    dtprep_shrink<<<dim3(4, MROW / 64), 256, 0, stream>>>(
        ws + OFF_XDBL, 288, dtw[0], dtw[1], dtb[0], dtb[1],
        ws + OFF_XS, Dvec,
        ws + OFF_DTT, ws + OFF_DUT, ws + OFF_UDT,
        bcmax, ws + OFF_BS, ws + OFF_CS);

    scan10_kernel<<<dim3(1024), 128, 0, stream>>>(ws, A_log, eps);

    transpose_yz_kernel<<<dim3(256 / 32, NROW / 32, 2), dim3(32, 8), 0, stream>>>(
        ws + OFF_YT, hb + HOFF_YZH, hb + HOFF_YZL);

    gemm_mfma<0, 0><<<dim3(512 / 128, MROW / 128), 256, 0, stream>>>(
        hb + HOFF_YZH, hb + HOFF_YZL, 512,
        hb + HOFF_OUTWH, hb + HOFF_OUTWL, WST_IN,
        out, 512, 512, 512, nullptr);
}

// Round 11
// 309.556 us; speedup vs baseline: 1.1314x; 1.0132x over previous
//
#include <hip/hip_runtime.h>
#include <math.h>

// ---------------- problem constants ----------------
constexpr int B_    = 2;
constexpr int L_    = 2048;
constexpr int NROW  = B_ * L_;     // 4096 rows per branch
constexpr int MROW  = 2 * NROW;    // 8192 merged rows (branch-major)
constexpr int HALF_ = 256;
constexpr int DS_   = 128;

constexpr float LOG2E = 1.4426950408889634f;

// ---------------- ws layout ----------------
// fp32 region (float element offsets)
constexpr size_t OFF_MINP = 0;                                    // 32 (minA partials)
constexpr size_t OFF_BCMX = 32;                                   // 4 (uint atomics: brB,brC x2)
constexpr size_t OFF_XZ   = 64;                                   // 8192x512 (transient)
constexpr size_t OFF_YT   = OFF_XZ + (size_t)MROW * 256;          // alias: 2x256x4096 (after conv)
constexpr size_t OFF_XDBL = OFF_XZ + (size_t)MROW * 512;          // 8192x288
constexpr size_t OFF_XS   = OFF_XDBL + (size_t)MROW * 288;        // 8192x256
constexpr size_t OFF_BS   = OFF_XS  + (size_t)MROW * 256;         // 2 x 4096x128
constexpr size_t OFF_CS   = OFF_BS  + (size_t)2 * NROW * 128;     // 2 x 4096x128
constexpr size_t OFF_DTT  = OFF_CS  + (size_t)2 * NROW * 128;     // 2 x 256x4096
constexpr size_t OFF_DUT  = OFF_DTT + (size_t)2 * 256 * 4096;
constexpr size_t OFF_UDT  = OFF_DUT + (size_t)2 * 256 * 4096;
constexpr size_t FLOAT_END = OFF_UDT + (size_t)2 * 256 * 4096;

// bf16 region (ushort element offsets, based at ws + FLOAT_END floats)
constexpr size_t HOFF_XINH = 0;                                   // 8192x512
constexpr size_t HOFF_XINL = HOFF_XINH + (size_t)MROW * 512;
constexpr size_t HOFF_YZH  = HOFF_XINH;                           // alias (xin dead after in_proj)
constexpr size_t HOFF_YZL  = HOFF_XINL;
constexpr size_t HOFF_XSH  = HOFF_XINL + (size_t)MROW * 512;      // 8192x256
constexpr size_t HOFF_XSL  = HOFF_XSH  + (size_t)MROW * 256;
constexpr size_t HOFF_INWH = HOFF_XSL  + (size_t)MROW * 256;      // 2 x 512x512
constexpr size_t HOFF_INWL = HOFF_INWH + 524288;
constexpr size_t HOFF_XWH  = HOFF_INWL + 524288;                  // 2 x 288x256
constexpr size_t HOFF_XWL  = HOFF_XWH  + 147456;
constexpr size_t HOFF_OUTWH= HOFF_XWL  + 147456;                  // 2 x 512x512
constexpr size_t HOFF_OUTWL= HOFF_OUTWH+ 524288;

constexpr size_t WST_IN = 262144;   // per-branch in/out weight elems
constexpr size_t WST_X  = 73728;    // per-branch x_proj weight elems

// pre_all block ranges
constexpr int PRE_MINA = 32;
constexpr int PRE_WSPL = (1196032 + 255) / 256;   // 4672
constexpr int PRE_TIN  = 64 * 16 * 4;             // 4096
constexpr int PRE_BLOCKS = PRE_MINA + PRE_WSPL + PRE_TIN;

// ---------------- types / helpers ----------------
typedef __bf16 bf16x8 __attribute__((ext_vector_type(8)));
typedef float  f32x4  __attribute__((ext_vector_type(4)));

__device__ __forceinline__ unsigned short bf16rn(float x) {
    unsigned u = __float_as_uint(x);
    unsigned r = (u + 0x7FFFu + ((u >> 16) & 1u)) >> 16;
    return (unsigned short)r;
}
__device__ __forceinline__ void split2(float x, unsigned short& h, unsigned short& l) {
    h = bf16rn(x);
    float hf = __uint_as_float(((unsigned)h) << 16);
    l = bf16rn(x - hf);
}

__device__ __forceinline__ float shrinkf(float v, float thr) {
    float a = fabsf(v) - thr;
    a = fmaxf(a, 0.0f);
    float r = copysignf(a, v);
    return (v == 0.0f) ? 0.0f : r;
}
__device__ __forceinline__ float siluf(float v) { return v / (1.0f + __expf(-v)); }
__device__ __forceinline__ float softplusf(float v) {
    return fmaxf(v, 0.0f) + log1pf(__expf(-fabsf(v)));
}
__device__ __forceinline__ float rlanef(float v, int l) {
    return __int_as_float(__builtin_amdgcn_readlane(__float_as_int(v), l));
}
// monotone float<->uint key for atomicMax on signed floats
__device__ __forceinline__ unsigned fkey(float f) {
    unsigned u = __float_as_uint(f);
    return (u >> 31) ? ~u : (u | 0x80000000u);
}
__device__ __forceinline__ float funkey(unsigned k) {
    unsigned u = (k >> 31) ? (k & 0x7FFFFFFFu) : ~k;
    return __uint_as_float(u);
}

// ---------------- pre_all: minA + weight splits + input transpose, one dispatch ----------------
__global__ __launch_bounds__(256) void pre_all(const float* __restrict__ A_log,
                                               const float* __restrict__ inp,
                                               const float* __restrict__ in_w0,
                                               const float* __restrict__ in_w1,
                                               const float* __restrict__ outw0,
                                               const float* __restrict__ outw1,
                                               const float* __restrict__ xw0,
                                               const float* __restrict__ xw1,
                                               float* __restrict__ ws,
                                               unsigned* __restrict__ bcmax,
                                               unsigned short* __restrict__ hb) {
    int bid = blockIdx.x;
    int tid = threadIdx.x;
    if (bid < PRE_MINA) {
        // ---- minA role ----
        __shared__ float sbuf[8];
        int i = bid * 1024 + tid * 4;
        float4 v = *(const float4*)(A_log + i);
        float mv = fminf(fminf(v.x, v.y), fminf(v.z, v.w));
        #pragma unroll
        for (int off = 32; off > 0; off >>= 1) mv = fminf(mv, __shfl_xor(mv, off));
        if ((tid & 63) == 0) sbuf[tid >> 6] = mv;
        __syncthreads();
        if (tid == 0) {
            float r = fminf(fminf(sbuf[0], sbuf[1]), fminf(sbuf[2], sbuf[3]));
            ws[OFF_MINP + bid] = r;
        }
        if (bid == 0 && tid < 4) bcmax[tid] = 0u;
    } else if (bid < PRE_MINA + PRE_WSPL) {
        // ---- wsplit role ----
        int i = (bid - PRE_MINA) * 256 + tid;
        if (i >= 1196032) return;
        const float* src;
        size_t hbase, lbase;
        int off;
        if (i < 1048576) {
            int t = i >> 18;
            off = i & 262143;
            src = (t == 0) ? in_w0 : (t == 1) ? in_w1 : (t == 2) ? outw0 : outw1;
            if (t < 2) { hbase = HOFF_INWH + (size_t)t * WST_IN;  lbase = HOFF_INWL + (size_t)t * WST_IN; }
            else       { hbase = HOFF_OUTWH + (size_t)(t - 2) * WST_IN; lbase = HOFF_OUTWL + (size_t)(t - 2) * WST_IN; }
        } else {
            int j = i - 1048576;
            int t = (j < (int)WST_X) ? 0 : 1;
            off = j - t * (int)WST_X;
            src = t ? xw1 : xw0;
            hbase = HOFF_XWH + (size_t)t * WST_X;
            lbase = HOFF_XWL + (size_t)t * WST_X;
        }
        unsigned short h, l;
        split2(src[off], h, l);
        hb[hbase + off] = h;
        hb[lbase + off] = l;
    } else {
        // ---- transpose_in role ----
        __shared__ float tile[32][33];
        int idx = bid - PRE_MINA - PRE_WSPL;    // 0..4095
        int bx = idx & 63;          // t block (64)
        int by = (idx >> 6) & 15;   // ch block (16)
        int z  = idx >> 10;         // 0..3
        int br = z >> 1;
        int b  = z & 1;
        int t0 = bx * 32;
        int m0 = by * 32;
        int tx = tid & 31;
        int ty = tid >> 5;
        #pragma unroll
        for (int k = 0; k < 4; k++) {
            tile[ty + 8 * k][tx] =
                inp[((size_t)b * 1024 + br * 512 + m0 + ty + 8 * k) * L_ + t0 + tx];
        }
        __syncthreads();
        #pragma unroll
        for (int k = 0; k < 4; k++) {
            size_t dst = ((size_t)br * NROW + (size_t)b * L_ + t0 + ty + 8 * k) * 512 + m0 + tx;
            unsigned short h, l;
            split2(tile[tx][ty + 8 * k], h, l);
            hb[HOFF_XINH + dst] = h;
            hb[HOFF_XINL + dst] = l;
        }
    }
}

// ---------------- MFMA GEMM (bf16x3), 128x128 tile ----------------
// Per k-step: 48 MFMA vs 8 staging loads + 8 LDS stores. LDS = 40960 B =
// exactly 4 blocks/CU. K-summation order per output column unchanged ->
// bit-identical results. Verified round 9: total 322.3 -> 313.6.
template <int NGUARD, int DOMAX>
__global__ __launch_bounds__(256) void gemm_mfma(const unsigned short* __restrict__ Ah,
                                                 const unsigned short* __restrict__ Al, int lda,
                                                 const unsigned short* __restrict__ WhB,
                                                 const unsigned short* __restrict__ WlB,
                                                 size_t wstride,
                                                 float* __restrict__ C, int ldc,
                                                 int N, int K,
                                                 unsigned* __restrict__ bcmax) {
    __shared__ __align__(16) unsigned short sAh[128 * 40];
    __shared__ __align__(16) unsigned short sAl[128 * 40];
    __shared__ __align__(16) unsigned short sBh[128 * 40];
    __shared__ __align__(16) unsigned short sBl[128 * 40];
    int tid  = threadIdx.x;
    int wid  = tid >> 6;
    int lane = tid & 63;
    int fr   = lane & 15;
    int kg   = lane >> 4;
    int mblk = blockIdx.y * 128;
    int nblk = blockIdx.x * 128;
    int br   = (mblk >= NROW) ? 1 : 0;
    const unsigned short* Wh = WhB + (size_t)br * wstride;
    const unsigned short* Wl = WlB + (size_t)br * wstride;
    int srow = tid >> 2;            // 0..63
    int skp  = (tid & 3) * 8;       // k-chunk of 8
    bool brow_ok0 = (!NGUARD) || ((nblk + srow) < N);
    bool brow_ok1 = (!NGUARD) || ((nblk + 64 + srow) < N);

    const unsigned short* pA0 = Ah + (size_t)(mblk + srow) * lda + skp;
    const unsigned short* pA1 = Ah + (size_t)(mblk + 64 + srow) * lda + skp;
    const unsigned short* pL0 = Al + (size_t)(mblk + srow) * lda + skp;
    const unsigned short* pL1 = Al + (size_t)(mblk + 64 + srow) * lda + skp;
    const unsigned short* pB0h = Wh + (size_t)(nblk + srow) * K + skp;
    const unsigned short* pB1h = Wh + (size_t)(nblk + 64 + srow) * K + skp;
    const unsigned short* pB0l = Wl + (size_t)(nblk + srow) * K + skp;
    const unsigned short* pB1l = Wl + (size_t)(nblk + 64 + srow) * K + skp;

    f32x4 acc[2][8] = {};

    uint4 rah0 = *(const uint4*)(pA0);
    uint4 rah1 = *(const uint4*)(pA1);
    uint4 ral0 = *(const uint4*)(pL0);
    uint4 ral1 = *(const uint4*)(pL1);
    uint4 rbh0 = {0, 0, 0, 0}, rbh1 = {0, 0, 0, 0};
    uint4 rbl0 = {0, 0, 0, 0}, rbl1 = {0, 0, 0, 0};
    if (brow_ok0) { rbh0 = *(const uint4*)(pB0h); rbl0 = *(const uint4*)(pB0l); }
    if (brow_ok1) { rbh1 = *(const uint4*)(pB1h); rbl1 = *(const uint4*)(pB1l); }

    for (int k0 = 0; k0 < K; k0 += 32) {
        __syncthreads();   // WAR vs previous iter's ds_reads
        *(uint4*)(sAh + srow * 40 + skp) = rah0;
        *(uint4*)(sAh + (64 + srow) * 40 + skp) = rah1;
        *(uint4*)(sAl + srow * 40 + skp) = ral0;
        *(uint4*)(sAl + (64 + srow) * 40 + skp) = ral1;
        *(uint4*)(sBh + srow * 40 + skp) = rbh0;
        *(uint4*)(sBh + (64 + srow) * 40 + skp) = rbh1;
        *(uint4*)(sBl + srow * 40 + skp) = rbl0;
        *(uint4*)(sBl + (64 + srow) * 40 + skp) = rbl1;
        __syncthreads();

        int kn = k0 + 32;
        if (kn < K) {      // prefetch next chunk; latency hides under MFMAs below
            rah0 = *(const uint4*)(pA0 + kn);
            rah1 = *(const uint4*)(pA1 + kn);
            ral0 = *(const uint4*)(pL0 + kn);
            ral1 = *(const uint4*)(pL1 + kn);
            if (brow_ok0) { rbh0 = *(const uint4*)(pB0h + kn); rbl0 = *(const uint4*)(pB0l + kn); }
            if (brow_ok1) { rbh1 = *(const uint4*)(pB1h + kn); rbl1 = *(const uint4*)(pB1l + kn); }
        }

        bf16x8 ah0 = *(const bf16x8*)(sAh + (wid * 32 + fr) * 40 + kg * 8);
        bf16x8 ah1 = *(const bf16x8*)(sAh + (wid * 32 + 16 + fr) * 40 + kg * 8);
        bf16x8 al0 = *(const bf16x8*)(sAl + (wid * 32 + fr) * 40 + kg * 8);
        bf16x8 al1 = *(const bf16x8*)(sAl + (wid * 32 + 16 + fr) * 40 + kg * 8);
        #pragma unroll
        for (int nt = 0; nt < 8; nt++) {
            bf16x8 bh = *(const bf16x8*)(sBh + (nt * 16 + fr) * 40 + kg * 8);
            bf16x8 bl = *(const bf16x8*)(sBl + (nt * 16 + fr) * 40 + kg * 8);
            acc[0][nt] = __builtin_amdgcn_mfma_f32_16x16x32_bf16(ah0, bh, acc[0][nt], 0, 0, 0);
            acc[0][nt] = __builtin_amdgcn_mfma_f32_16x16x32_bf16(ah0, bl, acc[0][nt], 0, 0, 0);
            acc[0][nt] = __builtin_amdgcn_mfma_f32_16x16x32_bf16(al0, bh, acc[0][nt], 0, 0, 0);
            acc[1][nt] = __builtin_amdgcn_mfma_f32_16x16x32_bf16(ah1, bh, acc[1][nt], 0, 0, 0);
            acc[1][nt] = __builtin_amdgcn_mfma_f32_16x16x32_bf16(ah1, bl, acc[1][nt], 0, 0, 0);
            acc[1][nt] = __builtin_amdgcn_mfma_f32_16x16x32_bf16(al1, bh, acc[1][nt], 0, 0, 0);
        }
    }
    // C/D layout: col = lane&15, row = (lane>>4)*4 + reg
    #pragma unroll
    for (int mt = 0; mt < 2; mt++) {
        #pragma unroll
        for (int nt = 0; nt < 8; nt++) {
            int col = nblk + nt * 16 + fr;
            if (NGUARD && col >= N) continue;
            #pragma unroll
            for (int r = 0; r < 4; r++) {
                int row = mblk + wid * 32 + mt * 16 + kg * 4 + r;
                C[(size_t)row * ldc + col] = acc[mt][nt][r];
            }
        }
    }
    if (DOMAX) {
        float mb = -INFINITY, mc = -INFINITY;
        #pragma unroll
        for (int nt = 0; nt < 8; nt++) {
            int c16 = nblk + nt * 16;
            if (c16 >= 32 && c16 < 160) {
                #pragma unroll
                for (int mt = 0; mt < 2; mt++)
                    #pragma unroll
                    for (int r = 0; r < 4; r++) mb = fmaxf(mb, acc[mt][nt][r]);
            } else if (c16 >= 160 && c16 < 288) {
                #pragma unroll
                for (int mt = 0; mt < 2; mt++)
                    #pragma unroll
                    for (int r = 0; r < 4; r++) mc = fmaxf(mc, acc[mt][nt][r]);
            }
        }
        #pragma unroll
        for (int off = 32; off > 0; off >>= 1) {
            mb = fmaxf(mb, __shfl_xor(mb, off));
            mc = fmaxf(mc, __shfl_xor(mc, off));
        }
        if (lane == 0) {
            if (mb > -INFINITY) atomicMax(bcmax + 2 * br,     fkey(mb));
            if (mc > -INFINITY) atomicMax(bcmax + 2 * br + 1, fkey(mc));
        }
    }
}

// ---------------- depthwise conv (k=4) + SiLU, vectorized 4 channels/thread ----------------
__global__ __launch_bounds__(256) void conv_silu_kernel(const float* __restrict__ xz,
                                                        float* __restrict__ xs,
                                                        unsigned short* __restrict__ xsh,
                                                        unsigned short* __restrict__ xsl,
                                                        unsigned short* __restrict__ yzh,
                                                        unsigned short* __restrict__ yzl,
                                                        const float* __restrict__ wx0,
                                                        const float* __restrict__ wx1,
                                                        const float* __restrict__ wz0,
                                                        const float* __restrict__ wz1) {
    int gid = blockIdx.x * 256 + threadIdx.x;   // over MROW*64
    int c4  = (gid & 63) << 2;                  // channel quad
    int row = gid >> 6;                         // global row 0..8191
    int br  = row >> 12;
    int t   = row & (L_ - 1);
    const float* wx = br ? wx1 : wx0;
    const float* wz = br ? wz1 : wz0;
    // per-channel taps (w[c][0..3] is exactly a float4)
    float4 wxv[4], wzv[4];
    #pragma unroll
    for (int k = 0; k < 4; k++) {
        wxv[k] = *(const float4*)(wx + (c4 + k) * 4);
        wzv[k] = *(const float4*)(wz + (c4 + k) * 4);
    }
    float4 ax = {0, 0, 0, 0}, az = {0, 0, 0, 0};
    #pragma unroll
    for (int j = 0; j < 4; j++) {
        int tt = t + j - 1;
        if (tt >= 0 && tt < L_) {
            const float* p = xz + (size_t)(row + j - 1) * 512;
            float4 vx = *(const float4*)(p + c4);
            float4 vz = *(const float4*)(p + 256 + c4);
            ax.x = fmaf(vx.x, ((const float*)&wxv[0])[j], ax.x);
            ax.y = fmaf(vx.y, ((const float*)&wxv[1])[j], ax.y);
            ax.z = fmaf(vx.z, ((const float*)&wxv[2])[j], ax.z);
            ax.w = fmaf(vx.w, ((const float*)&wxv[3])[j], ax.w);
            az.x = fmaf(vz.x, ((const float*)&wzv[0])[j], az.x);
            az.y = fmaf(vz.y, ((const float*)&wzv[1])[j], az.y);
            az.z = fmaf(vz.z, ((const float*)&wzv[2])[j], az.z);
            az.w = fmaf(vz.w, ((const float*)&wzv[3])[j], az.w);
        }
    }
    float4 sx, sz;
    sx.x = siluf(ax.x); sx.y = siluf(ax.y); sx.z = siluf(ax.z); sx.w = siluf(ax.w);
    sz.x = siluf(az.x); sz.y = siluf(az.y); sz.z = siluf(az.z); sz.w = siluf(az.w);
    *(float4*)(xs + (size_t)row * 256 + c4) = sx;
    ushort4 hx, lx, hz, lz;
    split2(sx.x, hx.x, lx.x); split2(sx.y, hx.y, lx.y);
    split2(sx.z, hx.z, lx.z); split2(sx.w, hx.w, lx.w);
    split2(sz.x, hz.x, lz.x); split2(sz.y, hz.y, lz.y);
    split2(sz.z, hz.z, lz.z); split2(sz.w, hz.w, lz.w);
    *(ushort4*)(xsh + (size_t)row * 256 + c4) = hx;
    *(ushort4*)(xsl + (size_t)row * 256 + c4) = lx;
    *(ushort4*)(yzh + (size_t)row * 512 + 256 + c4) = hz;
    *(ushort4*)(yzl + (size_t)row * 512 + 256 + c4) = lz;
}

// ---------------- fused dt_proj(K=32)+softplus+prep + shrinkpack ----------------
// grid (4, MROW/64). d-major outputs staged through LDS -> coalesced float4 stores.
__global__ __launch_bounds__(256) void dtprep_shrink(const float* __restrict__ A, int lda,
                                                     const float* __restrict__ W0,
                                                     const float* __restrict__ W1,
                                                     const float* __restrict__ b0,
                                                     const float* __restrict__ b1,
                                                     const float* __restrict__ xs,
                                                     const float* __restrict__ Dvec,
                                                     float* __restrict__ dtT,
                                                     float* __restrict__ duT,
                                                     float* __restrict__ udT,
                                                     const unsigned* __restrict__ bcmax,
                                                     float* __restrict__ Bs,
                                                     float* __restrict__ Cs) {
    __shared__ float As[16][68];
    __shared__ float Ws[16][68];
    __shared__ float tb[64 * 68];   // transpose buffer [n][m], stride 68 (16B-aligned rows)
    int tid = threadIdx.x;
    int kk = tid & 15;
    int rr = tid >> 4;
    int mblk = blockIdx.y * 64;
    int nblk = blockIdx.x * 64;
    int br = (mblk >= NROW) ? 1 : 0;
    const float* W    = br ? W1 : W0;
    const float* bias = br ? b1 : b0;
    float acc[4][4] = {};
    for (int k0 = 0; k0 < 32; k0 += 16) {
        #pragma unroll
        for (int j = 0; j < 4; j++) {
            As[kk][rr + 16 * j] = A[(size_t)(mblk + rr + 16 * j) * lda + k0 + kk];
        }
        #pragma unroll
        for (int j = 0; j < 4; j++) {
            Ws[kk][rr + 16 * j] = W[(size_t)(nblk + rr + 16 * j) * 32 + k0 + kk];
        }
        __syncthreads();
        int ty = tid >> 4;
        int tx = tid & 15;
        #pragma unroll
        for (int kq = 0; kq < 16; kq++) {
            float a0 = As[kq][ty * 4 + 0];
            float a1 = As[kq][ty * 4 + 1];
            float a2 = As[kq][ty * 4 + 2];
            float a3 = As[kq][ty * 4 + 3];
            float v0 = Ws[kq][tx * 4 + 0];
            float v1 = Ws[kq][tx * 4 + 1];
            float v2 = Ws[kq][tx * 4 + 2];
            float v3 = Ws[kq][tx * 4 + 3];
            acc[0][0] = fmaf(a0, v0, acc[0][0]); acc[0][1] = fmaf(a0, v1, acc[0][1]);
            acc[0][2] = fmaf(a0, v2, acc[0][2]); acc[0][3] = fmaf(a0, v3, acc[0][3]);
            acc[1][0] = fmaf(a1, v0, acc[1][0]); acc[1][1] = fmaf(a1, v1, acc[1][1]);
            acc[1][2] = fmaf(a1, v2, acc[1][2]); acc[1][3] = fmaf(a1, v3, acc[1][3]);
            acc[2][0] = fmaf(a2, v0, acc[2][0]); acc[2][1] = fmaf(a2, v1, acc[2][1]);
            acc[2][2] = fmaf(a2, v2, acc[2][2]); acc[2][3] = fmaf(a2, v3, acc[2][3]);
            acc[3][0] = fmaf(a3, v0, acc[3][0]); acc[3][1] = fmaf(a3, v1, acc[3][1]);
            acc[3][2] = fmaf(a3, v2, acc[3][2]); acc[3][3] = fmaf(a3, v3, acc[3][3]);
        }
        __syncthreads();
    }
    // epilogue: delta/u per (i,j); three d-major tensors via LDS transpose
    int ty = tid >> 4;
    int tx = tid & 15;
    float dlt[4][4], uu[4][4];
    #pragma unroll
    for (int i = 0; i < 4; i++) {
        int m = mblk + ty * 4 + i;
        #pragma unroll
        for (int j = 0; j < 4; j++) {
            int n = nblk + tx * 4 + j;
            dlt[i][j] = softplusf(acc[i][j] + bias[n]);
            uu[i][j]  = xs[(size_t)m * 256 + n];
        }
    }
    float Dv[4];
    #pragma unroll
    for (int j = 0; j < 4; j++) Dv[j] = Dvec[nblk + tx * 4 + j];

    int mlocbase = mblk & (NROW - 1);
    int nrd  = tid >> 2;              // 0..63: n-row to read
    int mc   = (tid & 3) * 4;         // starting float4 chunk
    size_t obase = ((size_t)br * 256 + nblk + nrd) * 4096 + mlocbase;
    #pragma unroll
    for (int pass = 0; pass < 3; pass++) {
        __syncthreads();   // WAR vs previous pass reads
        #pragma unroll
        for (int i = 0; i < 4; i++) {
            #pragma unroll
            for (int j = 0; j < 4; j++) {
                float v = (pass == 0) ? dlt[i][j] * LOG2E
                        : (pass == 1) ? dlt[i][j] * uu[i][j]
                                      : uu[i][j] * Dv[j];
                tb[(tx * 4 + j) * 68 + ty * 4 + i] = v;
            }
        }
        __syncthreads();
        float* dst = (pass == 0) ? dtT : (pass == 1) ? duT : udT;
        #pragma unroll
        for (int it = 0; it < 4; it++) {
            int cc = mc + it * 16;    // wait: cover 16 float4 chunks per n-row
            float4 v = *(const float4*)(tb + nrd * 68 + cc);
            *(float4*)(dst + obase + cc) = v;
        }
    }
    // ---- shrink slice: 64 rows x 64 cols of Bc or Cc ----
    {
        int q = blockIdx.x;
        int isC = q >> 1;
        int cbase = (q & 1) * 64;
        int xoff = isC ? (160 + cbase) : (32 + cbase);
        float thr = 0.1f * funkey(bcmax[2 * br + isC]);
        float* dstArr = isC ? Cs : Bs;
        int r = tid >> 2;
        int c0 = (tid & 3) * 16;
        const float* src = A + (size_t)(mblk + r) * lda + xoff + c0;
        float* dp = dstArr + (size_t)(mblk + r) * 128 + cbase + c0;
        #pragma unroll
        for (int i = 0; i < 16; i += 4) {
            float4 v = *(const float4*)(src + i);
            float4 o;
            o.x = shrinkf(v.x, thr);
            o.y = shrinkf(v.y, thr);
            o.z = shrinkf(v.z, thr);
            o.w = shrinkf(v.w, thr);
            *(float4*)(dp + i) = o;
        }
    }
}

// ---------------- selective scan v11: scan10 + depth-4 B/C ring + launch_bounds(128,1) ----------------
// scan10's stall analysis: occupancy is invariantly 2 waves/SIMD (131072
// lanes / 1024 SIMDs, chunking proved net-negative in r7), so the ~50us
// stall only shrinks via PREFETCH DISTANCE. Depth-2 ring distance = 1 phase
// ~ 160 cyc < L2-hit latency ~200 cyc (B/C is L2-resident, FETCH=20MB).
// v11: depth-4 ring -> distance 3 phases ~ 480 cyc > L2 latency. The r1/r2
// sinking failures were the PRESSURE-AWARE scheduler; launch_bounds(128,1)
// declares min 1 wave/EU -> 512-VGPR budget -> no pressure incentive to sink
// (occupancy is grid-limited anyway, so the relaxed bound costs nothing).
// Loop shape unchanged from scan10 (8 phases/c, m&3 slots compile-time,
// 8%4==0 -> slot mapping c-invariant). Tail over-read <= 3 phases lands in
// allocated ws regions (values unused).
// PRE-REGISTERED: VGPR >= 110 (ring resident; ~88 = sunk again -> revert),
// dur 95-110us, conflicts 0, absmax bit-identical.
__global__ __launch_bounds__(128, 1) void scan11_kernel(float* __restrict__ ws,
                                                        const float* __restrict__ A_log,
                                                        const float* __restrict__ eps) {
    int blk  = blockIdx.x;
    int xcd  = blk & 7;
    int slot = blk >> 3;
    int combo = xcd >> 1;
    int d  = (xcd & 1) * 128 + slot;
    int br = combo >> 1;
    int b  = combo & 1;
    int tid = threadIdx.x;
    int lt  = tid & 63;
    int half = tid >> 6;

    float pv = ws[OFF_MINP + (tid & 31)];
    #pragma unroll
    for (int off = 16; off > 0; off >>= 1) pv = fminf(pv, __shfl_xor(pv, off));
    float e  = 1.0f + eps[0];
    float m1 = -e * __expf(pv);
    float t1 = 0.1f * m1;
    float t2 = 0.1f * shrinkf(m1, t1);
    float base = -e * __expf(A_log[d * 128 + tid]);
    float a = shrinkf(base, t1);
    if (br) a = shrinkf(a, t2);

    size_t dchain = ((size_t)br * 256 + d) * 4096 + (size_t)b * L_;
    const float* dtp = ws + OFF_DTT + dchain;
    const float* dup = ws + OFF_DUT + dchain;
    const float* udp = ws + OFF_UDT + dchain;
    const float* Bq  = ws + OFF_BS + ((size_t)br * NROW + (size_t)b * L_) * 128 + tid;
    const float* Cq  = ws + OFF_CS + ((size_t)br * NROW + (size_t)b * L_) * 128 + tid;
    float*       yTp = ws + OFF_YT + dchain;

    // red: 64 timesteps x [wave0 cols 0..63 | wave1 cols 64..127 | pad 4].
    // Row stride 132 == 4 (mod 32): float4 reads have octet starting banks
    // {0,4,...,28} -> perfect 32-bank partition per 8 lanes -> conflict-free
    // (measured 0 across scan3/8/9/10). Writes lane-consecutive -> free.
    __shared__ float red[64 * 132];
    __shared__ float comb[2][64];

    float h = 0.0f;

    // depth-4 ring; Bq/Cq always point at the NEXT phase to fetch.
    float Bb[4][8], Cb[4][8];
    #pragma unroll
    for (int q = 0; q < 4; q++) {
        #pragma unroll
        for (int j = 0; j < 8; j++) { Bb[q][j] = Bq[j * 128]; Cb[q][j] = Cq[j * 128]; }
        Bq += 1024; Cq += 1024;
    }

    // per-lane dt/du (lane lt holds timestep lt of current c), prefetched 1 c ahead
    float dt_c = dtp[lt];
    float du_c = dup[lt];
    float dt_n = 0.0f, du_n = 0.0f;

    for (int c = 0; c < 32; c++) {
        if (c < 31) { dt_n = dtp[64 + lt]; du_n = dup[64 + lt]; }
        dtp += 64; dup += 64;
        // u*D for this c's 64 timesteps (branchless; wave1's value unused);
        // issued here, consumed at end of c -> full-c slack, vmcnt-counted.
        float ud_c = udp[c * 64 + lt];
        #pragma unroll
        for (int m = 0; m < 8; m++) {
            const int cur = m & 3;
            #pragma unroll
            for (int j = 0; j < 8; j++) {
                const int tl = m * 8 + j;              // readlane imm
                float dt2 = rlanef(dt_c, tl);
                float du  = rlanef(du_c, tl);
                float ev = __builtin_amdgcn_exp2f(dt2 * a);
                h = fmaf(ev, h, du * Bb[cur][j]);
                red[tl * 132 + half * 64 + lt] = h * Cb[cur][j];
            }
            // prefetch phase G+4 into the slot just consumed (distance = 3
            // full phases ~ 480 cyc > L2 latency; tail over-read safe junk)
            #pragma unroll
            for (int j = 0; j < 8; j++) {
                Bb[cur][j] = Bq[j * 128];
                Cb[cur][j] = Cq[j * 128];
            }
            Bq += 1024; Cq += 1024;
        }
        // wave-private reduce: lane lt sums its wave's 64 n-partials of
        // timestep lt (float4 at row stride 132 -> conflict-free).
        __builtin_amdgcn_wave_barrier();   // keep reads after this wave's writes
        {
            const float* rp = &red[lt * 132 + half * 64];
            float s0 = 0.f, s1 = 0.f, s2 = 0.f, s3 = 0.f;
            #pragma unroll
            for (int i = 0; i < 64; i += 4) {
                float4 v = *(const float4*)(rp + i);
                s0 += v.x; s1 += v.y; s2 += v.z; s3 += v.w;
            }
            float part = (s0 + s1) + (s2 + s3);
            if (half) comb[c & 1][lt] = part;
            __syncthreads();               // the ONLY block barrier per c
            if (!half) yTp[c * 64 + lt] = part + comb[c & 1][lt] + ud_c;
        }
        __builtin_amdgcn_wave_barrier();   // keep next c's writes after reads
        dt_c = dt_n;
        du_c = du_n;
    }
}

// ---------------- yT -> yz bf16 split (y half), merged: grid (8, 128, 2) ----------------
__global__ __launch_bounds__(256) void transpose_yz_kernel(const float* __restrict__ yT,
                                                           unsigned short* __restrict__ yzh,
                                                           unsigned short* __restrict__ yzl) {
    __shared__ float tile[32][33];
    int br = blockIdx.z;
    int m0 = blockIdx.x * 32;   // d rows
    int n0 = blockIdx.y * 32;   // within-branch t cols
    int tx = threadIdx.x;
    int ty = threadIdx.y;
    #pragma unroll
    for (int k = 0; k < 4; k++) {
        tile[ty + 8 * k][tx] = yT[((size_t)br * 256 + m0 + ty + 8 * k) * 4096 + n0 + tx];
    }
    __syncthreads();
    #pragma unroll
    for (int k = 0; k < 4; k++) {
        size_t dst = ((size_t)br * NROW + n0 + ty + 8 * k) * 512 + m0 + tx;
        unsigned short h, l;
        split2(tile[tx][ty + 8 * k], h, l);
        yzh[dst] = h; yzl[dst] = l;
    }
}

// ---------------- host-side launch ----------------
extern "C" void kernel_launch(void* const* d_in, const int* in_sizes, int n_in,
                              void* d_out, int out_size, void* d_ws, size_t ws_size,
                              hipStream_t stream) {
    const float* inp   = (const float*)d_in[0];
    const float* in_w[2]  = {(const float*)d_in[1],  (const float*)d_in[8]};
    const float* cxw[2]   = {(const float*)d_in[2],  (const float*)d_in[9]};
    const float* czw[2]   = {(const float*)d_in[3],  (const float*)d_in[10]};
    const float* xw[2]    = {(const float*)d_in[4],  (const float*)d_in[11]};
    const float* dtw[2]   = {(const float*)d_in[5],  (const float*)d_in[12]};
    const float* dtb[2]   = {(const float*)d_in[6],  (const float*)d_in[13]};
    const float* outw[2]  = {(const float*)d_in[7],  (const float*)d_in[14]};
    const float* A_log = (const float*)d_in[15];
    const float* Dvec  = (const float*)d_in[16];
    const float* eps   = (const float*)d_in[17];
    float* out = (float*)d_out;
    float* ws  = (float*)d_ws;
    unsigned short* hb = (unsigned short*)(ws + FLOAT_END);
    unsigned* bcmax = (unsigned*)(ws + OFF_BCMX);

    pre_all<<<PRE_BLOCKS, 256, 0, stream>>>(
        A_log, inp, in_w[0], in_w[1], outw[0], outw[1], xw[0], xw[1],
        ws, bcmax, hb);

    gemm_mfma<0, 0><<<dim3(512 / 128, MROW / 128), 256, 0, stream>>>(
        hb + HOFF_XINH, hb + HOFF_XINL, 512,
        hb + HOFF_INWH, hb + HOFF_INWL, WST_IN,
        ws + OFF_XZ, 512, 512, 512, nullptr);

    conv_silu_kernel<<<(MROW * 64) / 256, 256, 0, stream>>>(
        ws + OFF_XZ, ws + OFF_XS, hb + HOFF_XSH, hb + HOFF_XSL,
        hb + HOFF_YZH, hb + HOFF_YZL, cxw[0], cxw[1], czw[0], czw[1]);

    gemm_mfma<1, 1><<<dim3((288 + 127) / 128, MROW / 128), 256, 0, stream>>>(
        hb + HOFF_XSH, hb + HOFF_XSL, 256,
        hb + HOFF_XWH, hb + HOFF_XWL, WST_X,
        ws + OFF_XDBL, 288, 288, 256, bcmax);

    dtprep_shrink<<<dim3(4, MROW / 64), 256, 0, stream>>>(
        ws + OFF_XDBL, 288, dtw[0], dtw[1], dtb[0], dtb[1],
        ws + OFF_XS, Dvec,
        ws + OFF_DTT, ws + OFF_DUT, ws + OFF_UDT,
        bcmax, ws + OFF_BS, ws + OFF_CS);

    scan11_kernel<<<dim3(1024), 128, 0, stream>>>(ws, A_log, eps);

    transpose_yz_kernel<<<dim3(256 / 32, NROW / 32, 2), dim3(32, 8), 0, stream>>>(
        ws + OFF_YT, hb + HOFF_YZH, hb + HOFF_YZL);

    gemm_mfma<0, 0><<<dim3(512 / 128, MROW / 128), 256, 0, stream>>>(
        hb + HOFF_YZH, hb + HOFF_YZL, 512,
        hb + HOFF_OUTWH, hb + HOFF_OUTWL, WST_IN,
        out, 512, 512, 512, nullptr);
}